// Round 16
// baseline (437.531 us; speedup 1.0000x reference)
//
#include <hip/hip_runtime.h>
#include <cstdint>
#include <math.h>

#define TT 4
#define BB 16
#define CCH 512
#define HWD 1024
#define NHH 8
#define NW 16            // 512/32 channel bit-words
#define MQK 1.5e-4       // flag margin q/k (error std ~1.5e-5 -> 10 sigma)
#define MPROJ 1.0e-4     // flag margin proj
#define CAPQ 49152
#define CAPP 16384
#define WTSZ 262144      // ushorts per (mat,hi/lo) tile array: 32*16*64*8
#define XHOFF 12582912ULL            // byte offset of xh plane in ws
#define XPLANE 33554432ULL           // ushorts per plane (64 MiB)
#define WSNEED (XHOFF + 4ULL * XPLANE)   // ~146.8 MB

typedef __attribute__((ext_vector_type(4))) float f32x4;
typedef __attribute__((ext_vector_type(8))) short s16x8;
typedef __attribute__((ext_vector_type(4))) uint32_t u32x4;

static __device__ __forceinline__ f32x4 MFMA(s16x8 a, s16x8 b, f32x4 c) {
    return __builtin_amdgcn_mfma_f32_16x16x32_bf16(a, b, c, 0, 0, 0);
}

// high halves of u0,u1 -> one u32 (low word = u0's hi)
static __device__ __forceinline__ uint32_t hi_pair(uint32_t u0, uint32_t u1) {
#if __has_builtin(__builtin_amdgcn_perm)
    return __builtin_amdgcn_perm(u1, u0, 0x07060302u);
#else
    return (u1 & 0xFFFF0000u) | (u0 >> 16);
#endif
}
// low halves of u0,u1 -> one u32 (low word = u0's lo)
static __device__ __forceinline__ uint32_t lo_pair(uint32_t u0, uint32_t u1) {
#if __has_builtin(__builtin_amdgcn_perm)
    return __builtin_amdgcn_perm(u1, u0, 0x05040100u);
#else
    return ((u1 & 0xFFFFu) << 16) | (u0 & 0xFFFFu);
#endif
}

struct SplitPair { uint32_t h, l; };

// truncation split: x = bf(h) + bf(l) + r, |r| <= 2^-15 |x|
static __device__ __forceinline__ SplitPair split_pair(float f0, float f1) {
    const uint32_t u0 = __builtin_bit_cast(uint32_t, f0);
    const uint32_t u1 = __builtin_bit_cast(uint32_t, f1);
    SplitPair r;
    r.h = hi_pair(u0, u1);
    const float r0 = f0 - __builtin_bit_cast(float, u0 & 0xFFFF0000u);
    const float r1 = f1 - __builtin_bit_cast(float, u1 & 0xFFFF0000u);
    r.l = hi_pair(__builtin_bit_cast(uint32_t, r0), __builtin_bit_cast(uint32_t, r1));
    return r;
}

// pack one float -> (hi-bf16 << 16) | lo-bf16, truncation split
static __device__ __forceinline__ uint32_t packsplit(float f) {
    const uint32_t u = __builtin_bit_cast(uint32_t, f);
    const uint32_t hi = u & 0xFFFF0000u;
    const float r = f - __builtin_bit_cast(float, hi);
    return hi | (__builtin_bit_cast(uint32_t, r) >> 16);
}

static __device__ __forceinline__ void load_split_frag(const float* p, s16x8& h, s16x8& l) {
    const float4 a = *(const float4*)p;
    const float4 b4 = *(const float4*)(p + 4);
    u32x4 hw_, lw_;
    const SplitPair p0 = split_pair(a.x, a.y);
    const SplitPair p1 = split_pair(a.z, a.w);
    const SplitPair p2 = split_pair(b4.x, b4.y);
    const SplitPair p3 = split_pair(b4.z, b4.w);
    hw_[0] = p0.h; lw_[0] = p0.l;
    hw_[1] = p1.h; lw_[1] = p1.l;
    hw_[2] = p2.h; lw_[2] = p2.l;
    hw_[3] = p3.h; lw_[3] = p3.l;
    h = __builtin_bit_cast(s16x8, hw_);
    l = __builtin_bit_cast(s16x8, lw_);
}

// async global->LDS 16B per lane (LDS dest = wave-uniform base + lane*16)
static __device__ __forceinline__ void glds16(const float* g, float* l) {
    __builtin_amdgcn_global_load_lds(
        (const __attribute__((address_space(1))) uint32_t*)g,
        (__attribute__((address_space(3))) uint32_t*)l, 16, 0, 0);
}

// ---------------------------------------------------------------------------
// Layout self-probe for mfma_f32_16x16x32_bf16 (verified on HW in R6-R15).
// ---------------------------------------------------------------------------
static __device__ __forceinline__ void probe_bf16(int lane, int rowD[4], int colD[4],
                                                  int& aRow, int& aKb, int& bCol, int& bKb)
{
    const f32x4 z = {0.f, 0.f, 0.f, 0.f};
    const short lv = (short)(__builtin_bit_cast(uint32_t, (float)lane) >> 16);
    const short one = (short)0x3F80;
    const s16x8 av = {lv, lv, lv, lv, lv, lv, lv, lv};
    const s16x8 ov = {one, one, one, one, one, one, one, one};
    const f32x4 pa = MFMA(av, ov, z);
    const f32x4 pb = MFMA(ov, av, z);
    bool A2 = false, B2 = false;
#pragma unroll
    for (int r = 0; r < 4; ++r) {
        const int va = (int)pa[r];
        if (((va - 48) & 127) == 0) { rowD[r] = (va - 48) >> 7; A2 = true; }
        else                        { rowD[r] = (va - 768) >> 5; }
        const int vb = (int)pb[r];
        if (((vb - 48) & 127) == 0) { colD[r] = (vb - 48) >> 7; B2 = true; }
        else                        { colD[r] = (vb - 768) >> 5; }
    }
    aRow = A2 ? (lane >> 2) : (lane & 15);
    aKb  = A2 ? (lane & 3) * 8 : (lane >> 4) * 8;
    bCol = B2 ? (lane >> 2) : (lane & 15);
    bKb  = B2 ? (lane & 3) * 8 : (lane >> 4) * 8;
}

__global__ void k_zero(unsigned int* ctr) {
    if (threadIdx.x < 2) ctr[threadIdx.x] = 0u;
}

// ---------------------------------------------------------------------------
// Pre-split + transpose x: f32 [tb][c][hw] -> bf16 planes xh/xl [tb][hw][c].
// LDS-tiled (32c x 64hw), coalesced both sides. Bandwidth-bound.
// ---------------------------------------------------------------------------
__global__ __launch_bounds__(256) void k_xsplit(
    const float* __restrict__ x,
    unsigned short* __restrict__ xh, unsigned short* __restrict__ xl)
{
    __shared__ uint32_t T[32][65];
    const int tid = threadIdx.x;
    const int tb = blockIdx.z;
    const int c0 = blockIdx.y * 32, hw0 = blockIdx.x * 64;

    {
        const int c = tid >> 3, hwq = (tid & 7) * 8;
        const float* src = &x[((size_t)tb * CCH + c0 + c) * HWD + hw0 + hwq];
        const float4 a = *(const float4*)src;
        const float4 b4 = *(const float4*)(src + 4);
        T[c][hwq + 0] = packsplit(a.x);  T[c][hwq + 1] = packsplit(a.y);
        T[c][hwq + 2] = packsplit(a.z);  T[c][hwq + 3] = packsplit(a.w);
        T[c][hwq + 4] = packsplit(b4.x); T[c][hwq + 5] = packsplit(b4.y);
        T[c][hwq + 6] = packsplit(b4.z); T[c][hwq + 7] = packsplit(b4.w);
    }
    __syncthreads();
    {
        const int hw = tid >> 2, cq = (tid & 3) * 8;
        uint32_t v[8];
#pragma unroll
        for (int j = 0; j < 8; ++j) v[j] = T[cq + j][hw];
        u32x4 h, l;
#pragma unroll
        for (int p = 0; p < 4; ++p) {
            h[p] = hi_pair(v[2 * p], v[2 * p + 1]);
            l[p] = lo_pair(v[2 * p], v[2 * p + 1]);
        }
        const size_t off = ((size_t)tb * HWD + hw0 + hw) * CCH + c0 + cq;
        *(u32x4*)&xh[off] = h;
        *(u32x4*)&xl[off] = l;
    }
}

// ---------------------------------------------------------------------------
// Pre-pass: split q/k/proj weights into canonical MFMA-frag hi/lo tiles:
//   wt[(mat*2+hl)*WTSZ + ((ot*16+ks)*64 + kgrp*16 + row)*8 + e]
// and precompute fp64 BN constants (proj bias folded into add).
// ---------------------------------------------------------------------------
__global__ __launch_bounds__(256) void k_prep(
    const float* __restrict__ qw, const float* __restrict__ kw, const float* __restrict__ pw,
    const float* __restrict__ qg, const float* __restrict__ qbe,
    const float* __restrict__ qm, const float* __restrict__ qva,
    const float* __restrict__ kg, const float* __restrict__ kbe,
    const float* __restrict__ km, const float* __restrict__ kva,
    const float* __restrict__ pg, const float* __restrict__ pbe,
    const float* __restrict__ pm, const float* __restrict__ pva,
    const float* __restrict__ pb,
    unsigned short* __restrict__ wt, double* __restrict__ bnc)
{
    const int bx = blockIdx.x;        // 0..95
    const int mat = bx >> 5, ot = bx & 31;
    const float* W = (mat == 0) ? qw : ((mat == 1) ? kw : pw);
    unsigned short* hi = wt + (size_t)(mat * 2 + 0) * WTSZ;
    unsigned short* lo = wt + (size_t)(mat * 2 + 1) * WTSZ;
#pragma unroll
    for (int it = 0; it < 4; ++it) {
        const int j = it * 256 + threadIdx.x;   // 0..1023 chunk index
        const int ks = j >> 6, sub = j & 63;
        const int kgrp = sub >> 4, row = sub & 15;
        const float* src = W + (size_t)(ot * 16 + row) * CCH + ks * 32 + kgrp * 8;
        s16x8 h, l;
        load_split_frag(src, h, l);
        *(s16x8*)&hi[((size_t)(ot * 16 + ks) * 64 + sub) * 8] = h;
        *(s16x8*)&lo[((size_t)(ot * 16 + ks) * 64 + sub) * 8] = l;
    }
    if (ot == 0) {
        const float* g  = (mat == 0) ? qg  : ((mat == 1) ? kg  : pg);
        const float* be = (mat == 0) ? qbe : ((mat == 1) ? kbe : pbe);
        const float* mn = (mat == 0) ? qm  : ((mat == 1) ? km  : pm);
        const float* va = (mat == 0) ? qva : ((mat == 1) ? kva : pva);
        for (int o = threadIdx.x; o < CCH; o += 256) {
            const double inv = (double)g[o] / sqrt((double)va[o] + 1e-5);
            double add = (double)be[o] - (double)mn[o] * inv;
            if (mat == 2) add = add + (double)pb[o] * inv;
            bnc[(size_t)(mat * CCH + o) * 2]     = inv;
            bnc[(size_t)(mat * CCH + o) * 2 + 1] = add;
        }
    }
}

// ---------------------------------------------------------------------------
// q/k conv1x1 via bf16-split MFMA (3 cross terms), PRE-SPLIT path: x comes
// from transposed bf16 planes. B-frag = 2 x ds_read_b128, ZERO unpack VALU.
// glds stages [t4][hw32][c32] tiles per plane (XOR quadrant swizzle applied
// to the per-lane GLOBAL address; LDS linear). Double-buffered, one
// barrier/ks. Block = 64o x 32hw, 4 waves, wave = 32o (2 ot) x 16hw, 2 br.
// ---------------------------------------------------------------------------
__global__ __launch_bounds__(256, 4) void k_qk_pre(
    const unsigned short* __restrict__ xh, const unsigned short* __restrict__ xl,
    const unsigned short* __restrict__ wt, const double* __restrict__ bnc,
    uint32_t* __restrict__ qbits, uint32_t* __restrict__ kbits,
    unsigned int* __restrict__ ctr, uint32_t* __restrict__ list)
{
    __shared__ unsigned short XS[2][2][4096];   // [buf][plane][t*1024+hw*32+c]
    __shared__ uint32_t QB[2][2][TT][32];       // [branch][o-word][t][hw]

    const int tid = threadIdx.x, lane = tid & 63, wid = tid >> 6;
    const int b   = blockIdx.z;
    const int o0  = blockIdx.y * 64, hw0 = blockIdx.x * 32;
    const int worow = (wid >> 1) * 32, whw = (wid & 1) * 16;

    int rowD[4], colD[4], aRow, aKb, bCol, bKb;
    probe_bf16(lane, rowD, colD, aRow, aKb, bCol, bKb);

    const int laneoff = ((aKb >> 3) * 16 + aRow) * 8;   // A-frag offset in tile
    const int kgrp = bKb >> 3;
    const int hwl  = whw + bCol;
    const int physq = kgrp ^ ((hwl >> 1) & 3);          // XOR quadrant swizzle
    const int boff  = (hwl * 4 + physq) * 8;            // + t*1024 (ushorts)
    const int otg0 = blockIdx.y * 4 + (wid >> 1) * 2;   // first 16-o tile idx

    // glds source offsets: chunk ch' = it*256+tid; plane = it>>1;
    // ch = (it&1)*256+tid -> t = ch>>7, hw = (ch>>2)&31, pq = ch&3
    uint32_t gO[4];
#pragma unroll
    for (int it = 0; it < 4; ++it) {
        const int ch = (it & 1) * 256 + tid;
        const int t = ch >> 7, hw = (ch >> 2) & 31, pq = ch & 3;
        gO[it] = (uint32_t)(((size_t)(t * BB + b) * HWD + hw0 + hw) * CCH
                            + (pq ^ ((hw >> 1) & 3)) * 8);
    }

    f32x4 aq[TT][2], ak[TT][2];
#pragma unroll
    for (int t = 0; t < TT; ++t)
#pragma unroll
        for (int ot = 0; ot < 2; ++ot) {
            aq[t][ot] = (f32x4){0.f, 0.f, 0.f, 0.f};
            ak[t][ot] = (f32x4){0.f, 0.f, 0.f, 0.f};
        }

    auto stage = [&](int ks, int buf) {
#pragma unroll
        for (int it = 0; it < 4; ++it) {
            const unsigned short* sp = (it >> 1) ? xl : xh;
            glds16((const float*)(sp + (size_t)gO[it] + ks * 32),
                   (float*)&XS[buf][it >> 1][((it & 1) * 256 + wid * 64) * 8]);
        }
    };

    stage(0, 0);

    int cur = 0;
#pragma unroll 1
    for (int ks = 0; ks < 16; ++ks) {
        __syncthreads();                    // glds(ks) complete; buf cur^1 free
        if (ks < 15) stage(ks + 1, cur ^ 1);

        const size_t tb0 = ((size_t)(otg0 + 0) * 16 + ks) * 512 + laneoff;
        const size_t tb1 = ((size_t)(otg0 + 1) * 16 + ks) * 512 + laneoff;
        const s16x8 Aqh0 = *(const s16x8*)&wt[0 * WTSZ + tb0];
        const s16x8 Aql0 = *(const s16x8*)&wt[1 * WTSZ + tb0];
        const s16x8 Akh0 = *(const s16x8*)&wt[2 * WTSZ + tb0];
        const s16x8 Akl0 = *(const s16x8*)&wt[3 * WTSZ + tb0];
        const s16x8 Aqh1 = *(const s16x8*)&wt[0 * WTSZ + tb1];
        const s16x8 Aql1 = *(const s16x8*)&wt[1 * WTSZ + tb1];
        const s16x8 Akh1 = *(const s16x8*)&wt[2 * WTSZ + tb1];
        const s16x8 Akl1 = *(const s16x8*)&wt[3 * WTSZ + tb1];

#pragma unroll
        for (int t = 0; t < TT; ++t) {
            const int off = t * 1024 + boff;
            const s16x8 Bh = *(const s16x8*)&XS[cur][0][off];
            const s16x8 Bl = *(const s16x8*)&XS[cur][1][off];

            aq[t][0] = MFMA(Aqh0, Bh, aq[t][0]);
            aq[t][0] = MFMA(Aqh0, Bl, aq[t][0]);
            aq[t][0] = MFMA(Aql0, Bh, aq[t][0]);
            ak[t][0] = MFMA(Akh0, Bh, ak[t][0]);
            ak[t][0] = MFMA(Akh0, Bl, ak[t][0]);
            ak[t][0] = MFMA(Akl0, Bh, ak[t][0]);
            aq[t][1] = MFMA(Aqh1, Bh, aq[t][1]);
            aq[t][1] = MFMA(Aqh1, Bl, aq[t][1]);
            aq[t][1] = MFMA(Aql1, Bh, aq[t][1]);
            ak[t][1] = MFMA(Akh1, Bh, ak[t][1]);
            ak[t][1] = MFMA(Akh1, Bl, ak[t][1]);
            ak[t][1] = MFMA(Akl1, Bh, ak[t][1]);
        }
        cur ^= 1;
    }

    // ---- epilogue: fp64 BN + LIF, flags, bitpack ----
    ((uint32_t*)QB)[tid] = 0u;
    ((uint32_t*)QB)[tid + 256] = 0u;
    __syncthreads();

    auto chains = [&](f32x4 (&acc)[TT][2], int br) {
#pragma unroll
        for (int ot = 0; ot < 2; ++ot)
#pragma unroll
            for (int r = 0; r < 4; ++r) {
                const int orow = worow + ot * 16 + rowD[r];    // 0..63
                const int o = o0 + orow;
                const double inv = bnc[(size_t)(br * CCH + o) * 2];
                const double add = bnc[(size_t)(br * CCH + o) * 2 + 1];
                const uint32_t bit = 1u << (orow & 31);
                const int ow = orow >> 5;
                const int hwq = whw + colD[r];                 // 0..31
                double v = 0.0; bool fl = false;
#pragma unroll
                for (int t = 0; t < TT; ++t) {
                    const double y = (double)acc[t][ot][r] * inv + add;
                    v = v + (y - v) * 0.5;
                    if (fabs(v - 1.0) < MQK) fl = true;
                    if (v >= 1.0) { atomicOr(&QB[br][ow][t][hwq], bit); v = 0.0; }
                }
                if (fl) {
                    const unsigned int idx = atomicAdd(ctr, 1u);
                    if (idx < CAPQ)
                        list[idx] = (uint32_t)((br << 23) | (o << 14) | (b << 10) | (hw0 + hwq));
                }
            }
    };
    chains(aq, 0);
    chains(ak, 1);
    __syncthreads();

#pragma unroll
    for (int u = 0; u < 2; ++u) {
        const int idx = tid + u * 256;   // 0..511
        const int br = idx >> 8, ow = (idx >> 7) & 1, t = (idx >> 5) & 3, hwq = idx & 31;
        uint32_t* dst = br ? kbits : qbits;
        dst[((size_t)(t * BB + b) * NW + (o0 >> 5) + ow) * HWD + hw0 + hwq] = QB[br][ow][t][hwq];
    }
}

// ---------------------------------------------------------------------------
// Fallback q/k kernel (R12 verbatim): read-side split, glds raw f32.
// ---------------------------------------------------------------------------
__global__ __launch_bounds__(256, 4) void k_qk(
    const float* __restrict__ x,
    const unsigned short* __restrict__ wt, const double* __restrict__ bnc,
    uint32_t* __restrict__ qbits, uint32_t* __restrict__ kbits,
    unsigned int* __restrict__ ctr, uint32_t* __restrict__ list)
{
    __shared__ float Xs[2][4096];           // [buf][t 4][c 32][hw-phys 32]
    __shared__ uint32_t QB[2][2][TT][32];   // [branch][o-word][t][hw]

    const int tid = threadIdx.x, lane = tid & 63, wid = tid >> 6;
    const int b   = blockIdx.z;
    const int o0  = blockIdx.y * 64, hw0 = blockIdx.x * 32;
    const int worow = (wid >> 1) * 32, whw = (wid & 1) * 16;

    int rowD[4], colD[4], aRow, aKb, bCol, bKb;
    probe_bf16(lane, rowD, colD, aRow, aKb, bCol, bKb);

    const int laneoff = ((aKb >> 3) * 16 + aRow) * 8;   // A-frag offset in tile
    const int kgrp = bKb >> 3;
    const int roff = (whw + bCol) ^ ((kgrp & 1) << 4);  // swizzled hw column
    const int otg0 = blockIdx.y * 4 + (wid >> 1) * 2;   // first 16-o tile idx

    uint32_t gOff[4];
#pragma unroll
    for (int it = 0; it < 4; ++it) {
        const int ch = it * 256 + tid;       // 0..1023
        const int t = ch >> 8, c = (ch >> 3) & 31, hw4p = ch & 7;
        const int ghw4 = hw4p ^ (((c >> 3) & 1) << 2);
        gOff[it] = (uint32_t)(((t * BB + b) * CCH + c) * HWD + hw0 + ghw4 * 4);
    }

    f32x4 aq[TT][2], ak[TT][2];
#pragma unroll
    for (int t = 0; t < TT; ++t)
#pragma unroll
        for (int ot = 0; ot < 2; ++ot) {
            aq[t][ot] = (f32x4){0.f, 0.f, 0.f, 0.f};
            ak[t][ot] = (f32x4){0.f, 0.f, 0.f, 0.f};
        }

    auto stage = [&](int ks, int buf) {
#pragma unroll
        for (int it = 0; it < 4; ++it)
            glds16(x + (size_t)gOff[it] + (size_t)ks * (32 * HWD),
                   &Xs[buf][(it * 256 + wid * 64) * 4]);
    };

    stage(0, 0);

    int cur = 0;
#pragma unroll 1
    for (int ks = 0; ks < 16; ++ks) {
        __syncthreads();                    // glds(ks) complete; buf cur^1 free
        if (ks < 15) stage(ks + 1, cur ^ 1);

        const size_t tb0 = ((size_t)(otg0 + 0) * 16 + ks) * 512 + laneoff;
        const size_t tb1 = ((size_t)(otg0 + 1) * 16 + ks) * 512 + laneoff;
        const s16x8 Aqh0 = *(const s16x8*)&wt[0 * WTSZ + tb0];
        const s16x8 Aql0 = *(const s16x8*)&wt[1 * WTSZ + tb0];
        const s16x8 Akh0 = *(const s16x8*)&wt[2 * WTSZ + tb0];
        const s16x8 Akl0 = *(const s16x8*)&wt[3 * WTSZ + tb0];
        const s16x8 Aqh1 = *(const s16x8*)&wt[0 * WTSZ + tb1];
        const s16x8 Aql1 = *(const s16x8*)&wt[1 * WTSZ + tb1];
        const s16x8 Akh1 = *(const s16x8*)&wt[2 * WTSZ + tb1];
        const s16x8 Akl1 = *(const s16x8*)&wt[3 * WTSZ + tb1];

        const float* Bb = Xs[cur];
#pragma unroll
        for (int t = 0; t < TT; ++t) {
            const float* Bp = Bb + (t * 32 + kgrp * 8) * 32 + roff;
            float w[8];
#pragma unroll
            for (int e = 0; e < 8; ++e) w[e] = Bp[e * 32];
            u32x4 bh, bl;
#pragma unroll
            for (int p = 0; p < 4; ++p) {
                const SplitPair sp = split_pair(w[2 * p], w[2 * p + 1]);
                bh[p] = sp.h; bl[p] = sp.l;
            }
            const s16x8 Bh = __builtin_bit_cast(s16x8, bh);
            const s16x8 Bl = __builtin_bit_cast(s16x8, bl);

            aq[t][0] = MFMA(Aqh0, Bh, aq[t][0]);
            aq[t][0] = MFMA(Aqh0, Bl, aq[t][0]);
            aq[t][0] = MFMA(Aql0, Bh, aq[t][0]);
            ak[t][0] = MFMA(Akh0, Bh, ak[t][0]);
            ak[t][0] = MFMA(Akh0, Bl, ak[t][0]);
            ak[t][0] = MFMA(Akl0, Bh, ak[t][0]);
            aq[t][1] = MFMA(Aqh1, Bh, aq[t][1]);
            aq[t][1] = MFMA(Aqh1, Bl, aq[t][1]);
            aq[t][1] = MFMA(Aql1, Bh, aq[t][1]);
            ak[t][1] = MFMA(Akh1, Bh, ak[t][1]);
            ak[t][1] = MFMA(Akh1, Bl, ak[t][1]);
            ak[t][1] = MFMA(Akl1, Bh, ak[t][1]);
        }
        cur ^= 1;
    }

    {
        int dum0, dum1, dum2, dum3;
        probe_bf16(lane, rowD, colD, dum0, dum1, dum2, dum3);
    }
    ((uint32_t*)QB)[tid] = 0u;
    ((uint32_t*)QB)[tid + 256] = 0u;
    __syncthreads();

    auto chains = [&](f32x4 (&acc)[TT][2], int br) {
#pragma unroll
        for (int ot = 0; ot < 2; ++ot)
#pragma unroll
            for (int r = 0; r < 4; ++r) {
                const int orow = worow + ot * 16 + rowD[r];    // 0..63
                const int o = o0 + orow;
                const double inv = bnc[(size_t)(br * CCH + o) * 2];
                const double add = bnc[(size_t)(br * CCH + o) * 2 + 1];
                const uint32_t bit = 1u << (orow & 31);
                const int ow = orow >> 5;
                const int hwq = whw + colD[r];                 // 0..31
                double v = 0.0; bool fl = false;
#pragma unroll
                for (int t = 0; t < TT; ++t) {
                    const double y = (double)acc[t][ot][r] * inv + add;
                    v = v + (y - v) * 0.5;
                    if (fabs(v - 1.0) < MQK) fl = true;
                    if (v >= 1.0) { atomicOr(&QB[br][ow][t][hwq], bit); v = 0.0; }
                }
                if (fl) {
                    const unsigned int idx = atomicAdd(ctr, 1u);
                    if (idx < CAPQ)
                        list[idx] = (uint32_t)((br << 23) | (o << 14) | (b << 10) | (hw0 + hwq));
                }
            }
    };
    chains(aq, 0);
    chains(ak, 1);
    __syncthreads();

#pragma unroll
    for (int u = 0; u < 2; ++u) {
        const int idx = tid + u * 256;   // 0..511
        const int br = idx >> 8, ow = (idx >> 7) & 1, t = (idx >> 5) & 3, hwq = idx & 31;
        uint32_t* dst = br ? kbits : qbits;
        dst[((size_t)(t * BB + b) * NW + (o0 >> 5) + ow) * HWD + hw0 + hwq] = QB[br][ow][t][hwq];
    }
}

// ---------------------------------------------------------------------------
// Exact fp64 recompute of flagged q/k chains; patch spike bits.
// ---------------------------------------------------------------------------
__global__ __launch_bounds__(256) void k_fix_qk(
    const float* __restrict__ x,
    const float* __restrict__ qw, const float* __restrict__ qg, const float* __restrict__ qbe,
    const float* __restrict__ qm, const float* __restrict__ qva,
    const float* __restrict__ kw, const float* __restrict__ kg, const float* __restrict__ kbe,
    const float* __restrict__ km, const float* __restrict__ kva,
    const unsigned int* __restrict__ ctr, const uint32_t* __restrict__ list,
    uint32_t* __restrict__ qbits, uint32_t* __restrict__ kbits)
{
    const int lane = threadIdx.x & 63;
    const int wg = (blockIdx.x * blockDim.x + threadIdx.x) >> 6;
    const int nw = (gridDim.x * blockDim.x) >> 6;
    unsigned int n = *ctr; if (n > CAPQ) n = CAPQ;

    for (unsigned int i = wg; i < n; i += nw) {
        const uint32_t e = list[i];
        const int br = (e >> 23) & 1, o = (e >> 14) & 511, b = (e >> 10) & 15, hw = e & 1023;
        const float* w = (br ? kw : qw) + (size_t)o * CCH;
        double dots[TT];
#pragma unroll
        for (int t = 0; t < TT; ++t) {
            double s = 0.0;
            for (int c = lane; c < CCH; c += 64)
                s += (double)w[c] * (double)x[((size_t)(t * BB + b) * CCH + c) * HWD + hw];
#pragma unroll
            for (int off = 32; off; off >>= 1) s += __shfl_xor(s, off);
            dots[t] = s;
        }
        if (lane == 0) {
            const float* g  = br ? kg  : qg;
            const float* be = br ? kbe : qbe;
            const float* mn = br ? km  : qm;
            const float* va = br ? kva : qva;
            const double inv = (double)g[o] / sqrt((double)va[o] + 1e-5);
            const double add = (double)be[o] - (double)mn[o] * inv;
            uint32_t* bits = br ? kbits : qbits;
            double v = 0.0;
#pragma unroll
            for (int t = 0; t < TT; ++t) {
                const double y = dots[t] * inv + add;
                v = v + (y - v) * 0.5;
                const size_t wa = ((size_t)(t * BB + b) * NW + (o >> 5)) * HWD + hw;
                const uint32_t bit = 1u << (o & 31);
                if (v >= 1.0) { atomicOr(&bits[wa], bit); v = 0.0; }
                else          { atomicAnd(&bits[wa], ~bit); }
            }
        }
    }
}

// ---------------------------------------------------------------------------
// Head-sum of q spikes (popcount) + LIF at 0.5 (exact dyadic).
// ---------------------------------------------------------------------------
__global__ __launch_bounds__(256) void k_attn(
    const uint32_t* __restrict__ qbits, uint8_t* __restrict__ attn)
{
    const int idx = blockIdx.x * 256 + threadIdx.x;
    const int hw = idx & (HWD - 1);
    const int h  = (idx >> 10) & (NHH - 1);
    const int b  = idx >> 13;
    double v = 0.0;
#pragma unroll
    for (int t = 0; t < TT; ++t) {
        const uint32_t w0 = qbits[((size_t)(t * BB + b) * NW + h * 2    ) * HWD + hw];
        const uint32_t w1 = qbits[((size_t)(t * BB + b) * NW + h * 2 + 1) * HWD + hw];
        const double q = (double)(__popc(w0) + __popc(w1));
        v = v + (q - v) * 0.5;
        const uint8_t s = (v >= 0.5) ? (uint8_t)1 : (uint8_t)0;
        attn[((size_t)(t * BB + b) * NHH + h) * HWD + hw] = s;
        if (s) v = 0.0;
    }
}

// ---------------------------------------------------------------------------
// proj conv via bf16 MFMA over binary y = attn & k. A hi/lo planes staged
// per-ks via global_load_lds, double-buffered; kv/av prefetched one ks
// ahead. fp64 bias/BN/LIF + flags. Block = 128o x 32hw, 4 waves. [R15]
// ---------------------------------------------------------------------------
__global__ __launch_bounds__(256, 3) void k_proj(
    const unsigned short* __restrict__ wt, const double* __restrict__ bnc,
    const uint32_t* __restrict__ kbits, const uint8_t* __restrict__ attn,
    float* __restrict__ out,
    unsigned int* __restrict__ ctr2, uint32_t* __restrict__ list2)
{
    __shared__ __align__(16) unsigned short Aw[2][2][8][512];

    const int tid = threadIdx.x, lane = tid & 63, wid = tid >> 6;
    const int b   = blockIdx.z;
    const int o0  = blockIdx.y * 128, hw0 = blockIdx.x * 32;
    const int worow = (wid >> 1) * 64, whw = (wid & 1) * 16;

    int rowD[4], colD[4], aRow, aKb, bCol, bKb;
    probe_bf16(lane, rowD, colD, aRow, aKb, bCol, bKb);
    const int laneoff = ((aKb >> 3) * 16 + aRow) * 8;
    const int hwB = hw0 + whw + bCol;
    const int otl0 = (wid >> 1) * 4;

    f32x4 acc[TT][4];
#pragma unroll
    for (int t = 0; t < TT; ++t)
#pragma unroll
        for (int ot = 0; ot < 4; ++ot) acc[t][ot] = (f32x4){0.f, 0.f, 0.f, 0.f};

    auto stageA = [&](int ks, int buf) {
#pragma unroll
        for (int i = 0; i < 4; ++i) {
            const int ch = wid * 4 + i;       // 0..15
            const int plane = ch >> 3, otl = ch & 7;
            const unsigned short* src = wt + (size_t)(4 + plane) * WTSZ
                + ((size_t)(blockIdx.y * 8 + otl) * 16 + ks) * 512 + (size_t)lane * 8;
            glds16((const float*)src, (float*)&Aw[buf][plane][otl][0]);
        }
    };

    uint32_t kvc[TT], avc[TT], kvn[TT], avn[TT];
    auto loadB = [&](int ks, uint32_t kv[TT], uint32_t av[TT]) {
#pragma unroll
        for (int t = 0; t < TT; ++t) {
            const size_t tb = (size_t)(t * BB + b);
            kv[t] = kbits[(tb * NW + ks) * HWD + hwB];
            av[t] = attn[(tb * NHH + (ks >> 1)) * HWD + hwB];
        }
    };

    stageA(0, 0);
    loadB(0, kvc, avc);
    __syncthreads();

    int cur = 0;
#pragma unroll 1
    for (int ks = 0; ks < 16; ++ks) {
        if (ks < 15) { stageA(ks + 1, cur ^ 1); loadB(ks + 1, kvn, avn); }

        s16x8 Ah[4], Al[4];
#pragma unroll
        for (int ot = 0; ot < 4; ++ot) {
            Ah[ot] = *(const s16x8*)&Aw[cur][0][otl0 + ot][laneoff];
            Al[ot] = *(const s16x8*)&Aw[cur][1][otl0 + ot][laneoff];
        }
#pragma unroll
        for (int t = 0; t < TT; ++t) {
            const uint32_t mask = avc[t] ? kvc[t] : 0u;
            const uint32_t byt = (mask >> bKb) & 0xFFu;
            u32x4 bw;
#pragma unroll
            for (int j = 0; j < 4; ++j)
                bw[j] = (((byt >> (2 * j)) & 1u) ? 0x3F80u : 0u)
                      | (((byt >> (2 * j + 1)) & 1u) ? 0x3F800000u : 0u);
            const s16x8 By = __builtin_bit_cast(s16x8, bw);
#pragma unroll
            for (int ot = 0; ot < 4; ++ot) {
                acc[t][ot] = MFMA(Ah[ot], By, acc[t][ot]);
                acc[t][ot] = MFMA(Al[ot], By, acc[t][ot]);
            }
        }

        if (ks < 15) {
#pragma unroll
            for (int t = 0; t < TT; ++t) { kvc[t] = kvn[t]; avc[t] = avn[t]; }
        }
        __syncthreads();
        cur ^= 1;
    }

#pragma unroll
    for (int ot = 0; ot < 4; ++ot)
#pragma unroll
        for (int r = 0; r < 4; ++r) {
            const int o = o0 + worow + ot * 16 + rowD[r];
            const int hwD = hw0 + whw + colD[r];
            const double inv = bnc[(size_t)(2 * CCH + o) * 2];
            const double add = bnc[(size_t)(2 * CCH + o) * 2 + 1];
            double v = 0.0; bool fl = false;
#pragma unroll
            for (int t = 0; t < TT; ++t) {
                const double y = (double)acc[t][ot][r] * inv + add;
                v = v + (y - v) * 0.5;
                if (fabs(v - 1.0) < MPROJ) fl = true;
                float s;
                if (v >= 1.0) { s = 1.0f; v = 0.0; } else { s = 0.0f; }
                out[((size_t)(t * BB + b) * CCH + o) * HWD + hwD] = s;
            }
            if (fl) {
                const unsigned int idx = atomicAdd(ctr2, 1u);
                if (idx < CAPP) list2[idx] = (uint32_t)((o << 14) | (b << 10) | hwD);
            }
        }
}

// ---------------------------------------------------------------------------
// Exact fp64 recompute of flagged proj chains; patch d_out.
// ---------------------------------------------------------------------------
__global__ __launch_bounds__(256) void k_fix_proj(
    const float* __restrict__ pw, const float* __restrict__ pb,
    const float* __restrict__ pg, const float* __restrict__ pbe,
    const float* __restrict__ pm, const float* __restrict__ pva,
    const uint32_t* __restrict__ kbits, const uint8_t* __restrict__ attn,
    const unsigned int* __restrict__ ctr2, const uint32_t* __restrict__ list2,
    float* __restrict__ out)
{
    const int lane = threadIdx.x & 63;
    const int wg = (blockIdx.x * blockDim.x + threadIdx.x) >> 6;
    const int nw = (gridDim.x * blockDim.x) >> 6;
    unsigned int n = *ctr2; if (n > CAPP) n = CAPP;

    for (unsigned int i = wg; i < n; i += nw) {
        const uint32_t e = list2[i];
        const int o = (e >> 14) & 511, b = (e >> 10) & 15, hw = e & 1023;
        const float* w = pw + (size_t)o * CCH;
        double dots[TT];
#pragma unroll
        for (int t = 0; t < TT; ++t) {
            double s = 0.0;
            for (int c = lane; c < CCH; c += 64) {
                const uint32_t kv = kbits[((size_t)(t * BB + b) * NW + (c >> 5)) * HWD + hw];
                const uint32_t av = attn[((size_t)(t * BB + b) * NHH + (c >> 6)) * HWD + hw];
                if (av && ((kv >> (c & 31)) & 1u)) s += (double)w[c];
            }
#pragma unroll
            for (int off = 32; off; off >>= 1) s += __shfl_xor(s, off);
            dots[t] = s;
        }
        if (lane == 0) {
            const double inv = (double)pg[o] / sqrt((double)pva[o] + 1e-5);
            const double add = (double)pbe[o] - (double)pm[o] * inv;
            const double bias = (double)pb[o];
            double v = 0.0;
#pragma unroll
            for (int t = 0; t < TT; ++t) {
                const double y = (dots[t] + bias) * inv + add;
                v = v + (y - v) * 0.5;
                float s;
                if (v >= 1.0) { s = 1.0f; v = 0.0; } else { s = 0.0f; }
                out[((size_t)(t * BB + b) * CCH + o) * HWD + hw] = s;
            }
        }
    }
}

extern "C" void kernel_launch(void* const* d_in, const int* in_sizes, int n_in,
                              void* d_out, int out_size, void* d_ws, size_t ws_size,
                              hipStream_t stream)
{
    (void)in_sizes; (void)n_in; (void)out_size;

    const float* x   = (const float*)d_in[0];
    const float* qw  = (const float*)d_in[1];
    const float* qg  = (const float*)d_in[2];
    const float* qbe = (const float*)d_in[3];
    const float* qm  = (const float*)d_in[4];
    const float* qv  = (const float*)d_in[5];
    const float* kw  = (const float*)d_in[6];
    const float* kg  = (const float*)d_in[7];
    const float* kbe = (const float*)d_in[8];
    const float* km  = (const float*)d_in[9];
    const float* kv  = (const float*)d_in[10];
    const float* pw  = (const float*)d_in[11];
    const float* pb  = (const float*)d_in[12];
    const float* pg  = (const float*)d_in[13];
    const float* pbe = (const float*)d_in[14];
    const float* pm  = (const float*)d_in[15];
    const float* pv  = (const float*)d_in[16];

    uint8_t* base = (uint8_t*)d_ws;
    uint32_t* qbits = (uint32_t*)base;                              // 4 MiB
    uint32_t* kbits = (uint32_t*)(base + 4194304);                  // 4 MiB
    uint8_t*  attn  = base + 8388608;                               // 512 KiB
    unsigned int* ctr = (unsigned int*)(base + 8912896);            // 256 B
    uint32_t* qklist  = (uint32_t*)(base + 8913152);                // 192 KiB
    uint32_t* prlist  = (uint32_t*)(base + 9109760);                // 64 KiB
    unsigned short* wtiles = (unsigned short*)(base + 9175296);     // 3 MiB
    double* bnc = (double*)(base + 12321024);                       // 24 KiB
    unsigned short* xh = (unsigned short*)(base + XHOFF);           // 64 MiB
    unsigned short* xl = xh + XPLANE;                               // 64 MiB
    float* out = (float*)d_out;

    const bool pre = ws_size >= WSNEED;

    k_zero<<<1, 64, 0, stream>>>(ctr);
    k_prep<<<96, 256, 0, stream>>>(qw, kw, pw, qg, qbe, qm, qv,
                                   kg, kbe, km, kv, pg, pbe, pm, pv, pb,
                                   wtiles, bnc);
    if (pre) {
        k_xsplit<<<dim3(HWD / 64, CCH / 32, TT * BB), 256, 0, stream>>>(x, xh, xl);
        k_qk_pre<<<dim3(HWD / 32, CCH / 64, BB), 256, 0, stream>>>(
            xh, xl, wtiles, bnc, qbits, kbits, ctr, qklist);
    } else {
        k_qk<<<dim3(HWD / 32, CCH / 64, BB), 256, 0, stream>>>(
            x, wtiles, bnc, qbits, kbits, ctr, qklist);
    }
    k_fix_qk<<<256, 256, 0, stream>>>(x, qw, qg, qbe, qm, qv,
                                      kw, kg, kbe, km, kv, ctr, qklist, qbits, kbits);
    k_attn<<<(BB * NHH * HWD) / 256, 256, 0, stream>>>(qbits, attn);
    k_proj<<<dim3(HWD / 32, CCH / 128, BB), 256, 0, stream>>>(
        wtiles, bnc, kbits, attn, out, ctr + 1, prlist);
    k_fix_proj<<<64, 256, 0, stream>>>(pw, pb, pg, pbe, pm, pv,
                                       kbits, attn, ctr + 1, prlist, out);
}

// Round 17
// 429.734 us; speedup vs baseline: 1.0181x; 1.0181x over previous
//
#include <hip/hip_runtime.h>
#include <cstdint>
#include <math.h>

#define TT 4
#define BB 16
#define CCH 512
#define HWD 1024
#define NHH 8
#define NW 16            // 512/32 channel bit-words
#define MQK 1.5e-4       // flag margin q/k (error std ~1.5e-5 -> 10 sigma)
#define MPROJ 1.0e-4     // flag margin proj
#define CAPQ 49152
#define CAPP 16384
#define WTSZ 262144      // ushorts per (mat,hi/lo) tile array: 32*16*64*8

typedef __attribute__((ext_vector_type(4))) float f32x4;
typedef __attribute__((ext_vector_type(8))) short s16x8;
typedef __attribute__((ext_vector_type(4))) uint32_t u32x4;

static __device__ __forceinline__ f32x4 MFMA(s16x8 a, s16x8 b, f32x4 c) {
    return __builtin_amdgcn_mfma_f32_16x16x32_bf16(a, b, c, 0, 0, 0);
}

// high halves of u0,u1 -> one u32
static __device__ __forceinline__ uint32_t hi_pair(uint32_t u0, uint32_t u1) {
#if __has_builtin(__builtin_amdgcn_perm)
    return __builtin_amdgcn_perm(u1, u0, 0x07060302u);
#else
    return (u1 & 0xFFFF0000u) | (u0 >> 16);
#endif
}

struct SplitPair { uint32_t h, l; };

// truncation split: x = bf(h) + bf(l) + r, |r| <= 2^-15 |x|
static __device__ __forceinline__ SplitPair split_pair(float f0, float f1) {
    const uint32_t u0 = __builtin_bit_cast(uint32_t, f0);
    const uint32_t u1 = __builtin_bit_cast(uint32_t, f1);
    SplitPair r;
    r.h = hi_pair(u0, u1);
    const float r0 = f0 - __builtin_bit_cast(float, u0 & 0xFFFF0000u);
    const float r1 = f1 - __builtin_bit_cast(float, u1 & 0xFFFF0000u);
    r.l = hi_pair(__builtin_bit_cast(uint32_t, r0), __builtin_bit_cast(uint32_t, r1));
    return r;
}

static __device__ __forceinline__ void load_split_frag(const float* p, s16x8& h, s16x8& l) {
    const float4 a = *(const float4*)p;
    const float4 b4 = *(const float4*)(p + 4);
    u32x4 hw_, lw_;
    const SplitPair p0 = split_pair(a.x, a.y);
    const SplitPair p1 = split_pair(a.z, a.w);
    const SplitPair p2 = split_pair(b4.x, b4.y);
    const SplitPair p3 = split_pair(b4.z, b4.w);
    hw_[0] = p0.h; lw_[0] = p0.l;
    hw_[1] = p1.h; lw_[1] = p1.l;
    hw_[2] = p2.h; lw_[2] = p2.l;
    hw_[3] = p3.h; lw_[3] = p3.l;
    h = __builtin_bit_cast(s16x8, hw_);
    l = __builtin_bit_cast(s16x8, lw_);
}

// async global->LDS 16B per lane (LDS dest = wave-uniform base + lane*16)
static __device__ __forceinline__ void glds16(const float* g, float* l) {
    __builtin_amdgcn_global_load_lds(
        (const __attribute__((address_space(1))) uint32_t*)g,
        (__attribute__((address_space(3))) uint32_t*)l, 16, 0, 0);
}

// ---------------------------------------------------------------------------
// Layout self-probe for mfma_f32_16x16x32_bf16 (verified on HW in R6-R16).
// ---------------------------------------------------------------------------
static __device__ __forceinline__ void probe_bf16(int lane, int rowD[4], int colD[4],
                                                  int& aRow, int& aKb, int& bCol, int& bKb)
{
    const f32x4 z = {0.f, 0.f, 0.f, 0.f};
    const short lv = (short)(__builtin_bit_cast(uint32_t, (float)lane) >> 16);
    const short one = (short)0x3F80;
    const s16x8 av = {lv, lv, lv, lv, lv, lv, lv, lv};
    const s16x8 ov = {one, one, one, one, one, one, one, one};
    const f32x4 pa = MFMA(av, ov, z);
    const f32x4 pb = MFMA(ov, av, z);
    bool A2 = false, B2 = false;
#pragma unroll
    for (int r = 0; r < 4; ++r) {
        const int va = (int)pa[r];
        if (((va - 48) & 127) == 0) { rowD[r] = (va - 48) >> 7; A2 = true; }
        else                        { rowD[r] = (va - 768) >> 5; }
        const int vb = (int)pb[r];
        if (((vb - 48) & 127) == 0) { colD[r] = (vb - 48) >> 7; B2 = true; }
        else                        { colD[r] = (vb - 768) >> 5; }
    }
    aRow = A2 ? (lane >> 2) : (lane & 15);
    aKb  = A2 ? (lane & 3) * 8 : (lane >> 4) * 8;
    bCol = B2 ? (lane >> 2) : (lane & 15);
    bKb  = B2 ? (lane & 3) * 8 : (lane >> 4) * 8;
}

__global__ void k_zero(unsigned int* ctr) {
    if (threadIdx.x < 2) ctr[threadIdx.x] = 0u;
}

// ---------------------------------------------------------------------------
// Pre-pass: split q/k/proj weights into canonical MFMA-frag hi/lo tiles:
//   wt[(mat*2+hl)*WTSZ + ((ot*16+ks)*64 + kgrp*16 + row)*8 + e]
// and precompute fp64 BN constants (proj bias folded into add).
// ---------------------------------------------------------------------------
__global__ __launch_bounds__(256) void k_prep(
    const float* __restrict__ qw, const float* __restrict__ kw, const float* __restrict__ pw,
    const float* __restrict__ qg, const float* __restrict__ qbe,
    const float* __restrict__ qm, const float* __restrict__ qva,
    const float* __restrict__ kg, const float* __restrict__ kbe,
    const float* __restrict__ km, const float* __restrict__ kva,
    const float* __restrict__ pg, const float* __restrict__ pbe,
    const float* __restrict__ pm, const float* __restrict__ pva,
    const float* __restrict__ pb,
    unsigned short* __restrict__ wt, double* __restrict__ bnc)
{
    const int bx = blockIdx.x;        // 0..95
    const int mat = bx >> 5, ot = bx & 31;
    const float* W = (mat == 0) ? qw : ((mat == 1) ? kw : pw);
    unsigned short* hi = wt + (size_t)(mat * 2 + 0) * WTSZ;
    unsigned short* lo = wt + (size_t)(mat * 2 + 1) * WTSZ;
#pragma unroll
    for (int it = 0; it < 4; ++it) {
        const int j = it * 256 + threadIdx.x;   // 0..1023 chunk index
        const int ks = j >> 6, sub = j & 63;
        const int kgrp = sub >> 4, row = sub & 15;
        const float* src = W + (size_t)(ot * 16 + row) * CCH + ks * 32 + kgrp * 8;
        s16x8 h, l;
        load_split_frag(src, h, l);
        *(s16x8*)&hi[((size_t)(ot * 16 + ks) * 64 + sub) * 8] = h;
        *(s16x8*)&lo[((size_t)(ot * 16 + ks) * 64 + sub) * 8] = l;
    }
    if (ot == 0) {
        const float* g  = (mat == 0) ? qg  : ((mat == 1) ? kg  : pg);
        const float* be = (mat == 0) ? qbe : ((mat == 1) ? kbe : pbe);
        const float* mn = (mat == 0) ? qm  : ((mat == 1) ? km  : pm);
        const float* va = (mat == 0) ? qva : ((mat == 1) ? kva : pva);
        for (int o = threadIdx.x; o < CCH; o += 256) {
            const double inv = (double)g[o] / sqrt((double)va[o] + 1e-5);
            double add = (double)be[o] - (double)mn[o] * inv;
            if (mat == 2) add = add + (double)pb[o] * inv;
            bnc[(size_t)(mat * CCH + o) * 2]     = inv;
            bnc[(size_t)(mat * CCH + o) * 2 + 1] = add;
        }
    }
}

// ---------------------------------------------------------------------------
// q/k conv1x1 via bf16-split MFMA (3 cross terms). Block = 64o x 32hw,
// 4 waves (2 o-halves x 2 hw-halves), wave = 32o (2 ot) x 16hw, 2 branches.
// X staged RAW f32 via global_load_lds (swizzle on the per-lane GLOBAL
// address; LDS dest linear), double-buffered, one barrier per ks; bf16
// split at read time. fp64 BN/LIF epilogue, spikes bitpacked.  [R12 verbatim]
// ---------------------------------------------------------------------------
__global__ __launch_bounds__(256, 4) void k_qk(
    const float* __restrict__ x,
    const unsigned short* __restrict__ wt, const double* __restrict__ bnc,
    uint32_t* __restrict__ qbits, uint32_t* __restrict__ kbits,
    unsigned int* __restrict__ ctr, uint32_t* __restrict__ list)
{
    __shared__ float Xs[2][4096];           // [buf][t 4][c 32][hw-phys 32]
    __shared__ uint32_t QB[2][2][TT][32];   // [branch][o-word][t][hw]

    const int tid = threadIdx.x, lane = tid & 63, wid = tid >> 6;
    const int b   = blockIdx.z;
    const int o0  = blockIdx.y * 64, hw0 = blockIdx.x * 32;
    const int worow = (wid >> 1) * 32, whw = (wid & 1) * 16;

    int rowD[4], colD[4], aRow, aKb, bCol, bKb;
    probe_bf16(lane, rowD, colD, aRow, aKb, bCol, bKb);

    const int laneoff = ((aKb >> 3) * 16 + aRow) * 8;   // A-frag offset in tile
    const int kgrp = bKb >> 3;
    const int roff = (whw + bCol) ^ ((kgrp & 1) << 4);  // swizzled hw column
    const int otg0 = blockIdx.y * 4 + (wid >> 1) * 2;   // first 16-o tile idx

    uint32_t gOff[4];
#pragma unroll
    for (int it = 0; it < 4; ++it) {
        const int ch = it * 256 + tid;       // 0..1023
        const int t = ch >> 8, c = (ch >> 3) & 31, hw4p = ch & 7;
        const int ghw4 = hw4p ^ (((c >> 3) & 1) << 2);
        gOff[it] = (uint32_t)(((t * BB + b) * CCH + c) * HWD + hw0 + ghw4 * 4);
    }

    f32x4 aq[TT][2], ak[TT][2];
#pragma unroll
    for (int t = 0; t < TT; ++t)
#pragma unroll
        for (int ot = 0; ot < 2; ++ot) {
            aq[t][ot] = (f32x4){0.f, 0.f, 0.f, 0.f};
            ak[t][ot] = (f32x4){0.f, 0.f, 0.f, 0.f};
        }

    auto stage = [&](int ks, int buf) {
#pragma unroll
        for (int it = 0; it < 4; ++it)
            glds16(x + (size_t)gOff[it] + (size_t)ks * (32 * HWD),
                   &Xs[buf][(it * 256 + wid * 64) * 4]);
    };

    stage(0, 0);

    int cur = 0;
#pragma unroll 1
    for (int ks = 0; ks < 16; ++ks) {
        __syncthreads();                    // glds(ks) complete; buf cur^1 free
        if (ks < 15) stage(ks + 1, cur ^ 1);

        const size_t tb0 = ((size_t)(otg0 + 0) * 16 + ks) * 512 + laneoff;
        const size_t tb1 = ((size_t)(otg0 + 1) * 16 + ks) * 512 + laneoff;
        const s16x8 Aqh0 = *(const s16x8*)&wt[0 * WTSZ + tb0];
        const s16x8 Aql0 = *(const s16x8*)&wt[1 * WTSZ + tb0];
        const s16x8 Akh0 = *(const s16x8*)&wt[2 * WTSZ + tb0];
        const s16x8 Akl0 = *(const s16x8*)&wt[3 * WTSZ + tb0];
        const s16x8 Aqh1 = *(const s16x8*)&wt[0 * WTSZ + tb1];
        const s16x8 Aql1 = *(const s16x8*)&wt[1 * WTSZ + tb1];
        const s16x8 Akh1 = *(const s16x8*)&wt[2 * WTSZ + tb1];
        const s16x8 Akl1 = *(const s16x8*)&wt[3 * WTSZ + tb1];

        const float* Bb = Xs[cur];
#pragma unroll
        for (int t = 0; t < TT; ++t) {
            const float* Bp = Bb + (t * 32 + kgrp * 8) * 32 + roff;
            float w[8];
#pragma unroll
            for (int e = 0; e < 8; ++e) w[e] = Bp[e * 32];
            u32x4 bh, bl;
#pragma unroll
            for (int p = 0; p < 4; ++p) {
                const SplitPair sp = split_pair(w[2 * p], w[2 * p + 1]);
                bh[p] = sp.h; bl[p] = sp.l;
            }
            const s16x8 Bh = __builtin_bit_cast(s16x8, bh);
            const s16x8 Bl = __builtin_bit_cast(s16x8, bl);

            aq[t][0] = MFMA(Aqh0, Bh, aq[t][0]);
            aq[t][0] = MFMA(Aqh0, Bl, aq[t][0]);
            aq[t][0] = MFMA(Aql0, Bh, aq[t][0]);
            ak[t][0] = MFMA(Akh0, Bh, ak[t][0]);
            ak[t][0] = MFMA(Akh0, Bl, ak[t][0]);
            ak[t][0] = MFMA(Akl0, Bh, ak[t][0]);
            aq[t][1] = MFMA(Aqh1, Bh, aq[t][1]);
            aq[t][1] = MFMA(Aqh1, Bl, aq[t][1]);
            aq[t][1] = MFMA(Aql1, Bh, aq[t][1]);
            ak[t][1] = MFMA(Akh1, Bh, ak[t][1]);
            ak[t][1] = MFMA(Akh1, Bl, ak[t][1]);
            ak[t][1] = MFMA(Akl1, Bh, ak[t][1]);
        }
        cur ^= 1;
    }

    // ---- epilogue: fp64 BN + LIF, flags, bitpack ----
    {
        int dum0, dum1, dum2, dum3;
        probe_bf16(lane, rowD, colD, dum0, dum1, dum2, dum3);  // rematerialize
    }
    ((uint32_t*)QB)[tid] = 0u;
    ((uint32_t*)QB)[tid + 256] = 0u;
    __syncthreads();

    auto chains = [&](f32x4 (&acc)[TT][2], int br) {
#pragma unroll
        for (int ot = 0; ot < 2; ++ot)
#pragma unroll
            for (int r = 0; r < 4; ++r) {
                const int orow = worow + ot * 16 + rowD[r];    // 0..63
                const int o = o0 + orow;
                const double inv = bnc[(size_t)(br * CCH + o) * 2];
                const double add = bnc[(size_t)(br * CCH + o) * 2 + 1];
                const uint32_t bit = 1u << (orow & 31);
                const int ow = orow >> 5;
                const int hwq = whw + colD[r];                 // 0..31
                double v = 0.0; bool fl = false;
#pragma unroll
                for (int t = 0; t < TT; ++t) {
                    const double y = (double)acc[t][ot][r] * inv + add;
                    v = v + (y - v) * 0.5;
                    if (fabs(v - 1.0) < MQK) fl = true;
                    if (v >= 1.0) { atomicOr(&QB[br][ow][t][hwq], bit); v = 0.0; }
                }
                if (fl) {
                    const unsigned int idx = atomicAdd(ctr, 1u);
                    if (idx < CAPQ)
                        list[idx] = (uint32_t)((br << 23) | (o << 14) | (b << 10) | (hw0 + hwq));
                }
            }
    };
    chains(aq, 0);
    chains(ak, 1);
    __syncthreads();

#pragma unroll
    for (int u = 0; u < 2; ++u) {
        const int idx = tid + u * 256;   // 0..511
        const int br = idx >> 8, ow = (idx >> 7) & 1, t = (idx >> 5) & 3, hwq = idx & 31;
        uint32_t* dst = br ? kbits : qbits;
        dst[((size_t)(t * BB + b) * NW + (o0 >> 5) + ow) * HWD + hw0 + hwq] = QB[br][ow][t][hwq];
    }
}

// ---------------------------------------------------------------------------
// Exact fp64 recompute of flagged q/k chains; patch spike bits.
// ---------------------------------------------------------------------------
__global__ __launch_bounds__(256) void k_fix_qk(
    const float* __restrict__ x,
    const float* __restrict__ qw, const float* __restrict__ qg, const float* __restrict__ qbe,
    const float* __restrict__ qm, const float* __restrict__ qva,
    const float* __restrict__ kw, const float* __restrict__ kg, const float* __restrict__ kbe,
    const float* __restrict__ km, const float* __restrict__ kva,
    const unsigned int* __restrict__ ctr, const uint32_t* __restrict__ list,
    uint32_t* __restrict__ qbits, uint32_t* __restrict__ kbits)
{
    const int lane = threadIdx.x & 63;
    const int wg = (blockIdx.x * blockDim.x + threadIdx.x) >> 6;
    const int nw = (gridDim.x * blockDim.x) >> 6;
    unsigned int n = *ctr; if (n > CAPQ) n = CAPQ;

    for (unsigned int i = wg; i < n; i += nw) {
        const uint32_t e = list[i];
        const int br = (e >> 23) & 1, o = (e >> 14) & 511, b = (e >> 10) & 15, hw = e & 1023;
        const float* w = (br ? kw : qw) + (size_t)o * CCH;
        double dots[TT];
#pragma unroll
        for (int t = 0; t < TT; ++t) {
            double s = 0.0;
            for (int c = lane; c < CCH; c += 64)
                s += (double)w[c] * (double)x[((size_t)(t * BB + b) * CCH + c) * HWD + hw];
#pragma unroll
            for (int off = 32; off; off >>= 1) s += __shfl_xor(s, off);
            dots[t] = s;
        }
        if (lane == 0) {
            const float* g  = br ? kg  : qg;
            const float* be = br ? kbe : qbe;
            const float* mn = br ? km  : qm;
            const float* va = br ? kva : qva;
            const double inv = (double)g[o] / sqrt((double)va[o] + 1e-5);
            const double add = (double)be[o] - (double)mn[o] * inv;
            uint32_t* bits = br ? kbits : qbits;
            double v = 0.0;
#pragma unroll
            for (int t = 0; t < TT; ++t) {
                const double y = dots[t] * inv + add;
                v = v + (y - v) * 0.5;
                const size_t wa = ((size_t)(t * BB + b) * NW + (o >> 5)) * HWD + hw;
                const uint32_t bit = 1u << (o & 31);
                if (v >= 1.0) { atomicOr(&bits[wa], bit); v = 0.0; }
                else          { atomicAnd(&bits[wa], ~bit); }
            }
        }
    }
}

// ---------------------------------------------------------------------------
// Head-sum of q spikes (popcount) + LIF at 0.5 (exact dyadic).
// ---------------------------------------------------------------------------
__global__ __launch_bounds__(256) void k_attn(
    const uint32_t* __restrict__ qbits, uint8_t* __restrict__ attn)
{
    const int idx = blockIdx.x * 256 + threadIdx.x;
    const int hw = idx & (HWD - 1);
    const int h  = (idx >> 10) & (NHH - 1);
    const int b  = idx >> 13;
    double v = 0.0;
#pragma unroll
    for (int t = 0; t < TT; ++t) {
        const uint32_t w0 = qbits[((size_t)(t * BB + b) * NW + h * 2    ) * HWD + hw];
        const uint32_t w1 = qbits[((size_t)(t * BB + b) * NW + h * 2 + 1) * HWD + hw];
        const double q = (double)(__popc(w0) + __popc(w1));
        v = v + (q - v) * 0.5;
        const uint8_t s = (v >= 0.5) ? (uint8_t)1 : (uint8_t)0;
        attn[((size_t)(t * BB + b) * NHH + h) * HWD + hw] = s;
        if (s) v = 0.0;
    }
}

// ---------------------------------------------------------------------------
// proj conv via bf16 MFMA over binary y = attn & k. Block = 128o x 64hw,
// 8 waves (2 o-halves x 4 hw-quarters), wave = 64o (4 ot) x 16hw.
// A hi/lo planes staged per-ks via global_load_lds (shared by 4 hw-waves),
// double-buffered, one barrier/ks; kv/av prefetched one ks ahead.
// fp64 bias/BN/LIF + flags.
// ---------------------------------------------------------------------------
__global__ __launch_bounds__(512, 4) void k_proj(
    const unsigned short* __restrict__ wt, const double* __restrict__ bnc,
    const uint32_t* __restrict__ kbits, const uint8_t* __restrict__ attn,
    float* __restrict__ out,
    unsigned int* __restrict__ ctr2, uint32_t* __restrict__ list2)
{
    __shared__ __align__(16) unsigned short Aw[2][2][8][512];  // [buf][plane][otl][frag]

    const int tid = threadIdx.x, lane = tid & 63, wid = tid >> 6;
    const int b   = blockIdx.z;
    const int o0  = blockIdx.y * 128, hw0 = blockIdx.x * 64;
    const int worow = (wid >> 2) * 64, whw = (wid & 3) * 16;

    int rowD[4], colD[4], aRow, aKb, bCol, bKb;
    probe_bf16(lane, rowD, colD, aRow, aKb, bCol, bKb);
    const int laneoff = ((aKb >> 3) * 16 + aRow) * 8;
    const int hwB = hw0 + whw + bCol;
    const int otl0 = (wid >> 2) * 4;          // this wave's local ot base

    f32x4 acc[TT][4];
#pragma unroll
    for (int t = 0; t < TT; ++t)
#pragma unroll
        for (int ot = 0; ot < 4; ++ot) acc[t][ot] = (f32x4){0.f, 0.f, 0.f, 0.f};

    // glds staging: 16 chunks of 1KB (plane x 8 local ot tiles), 2 per wave
    auto stageA = [&](int ks, int buf) {
#pragma unroll
        for (int i = 0; i < 2; ++i) {
            const int ch = wid * 2 + i;       // 0..15
            const int plane = ch >> 3, otl = ch & 7;
            const unsigned short* src = wt + (size_t)(4 + plane) * WTSZ
                + ((size_t)(blockIdx.y * 8 + otl) * 16 + ks) * 512 + (size_t)lane * 8;
            glds16((const float*)src, (float*)&Aw[buf][plane][otl][0]);
        }
    };

    uint32_t kvc[TT], avc[TT], kvn[TT], avn[TT];
    auto loadB = [&](int ks, uint32_t kv[TT], uint32_t av[TT]) {
#pragma unroll
        for (int t = 0; t < TT; ++t) {
            const size_t tb = (size_t)(t * BB + b);
            kv[t] = kbits[(tb * NW + ks) * HWD + hwB];
            av[t] = attn[(tb * NHH + (ks >> 1)) * HWD + hwB];
        }
    };

    stageA(0, 0);
    loadB(0, kvc, avc);
    __syncthreads();                          // glds(0) complete

    int cur = 0;
#pragma unroll 1
    for (int ks = 0; ks < 16; ++ks) {
        if (ks < 15) { stageA(ks + 1, cur ^ 1); loadB(ks + 1, kvn, avn); }

        s16x8 Ah[4], Al[4];
#pragma unroll
        for (int ot = 0; ot < 4; ++ot) {
            Ah[ot] = *(const s16x8*)&Aw[cur][0][otl0 + ot][laneoff];
            Al[ot] = *(const s16x8*)&Aw[cur][1][otl0 + ot][laneoff];
        }
#pragma unroll
        for (int t = 0; t < TT; ++t) {
            const uint32_t mask = avc[t] ? kvc[t] : 0u;
            const uint32_t byt = (mask >> bKb) & 0xFFu;
            u32x4 bw;
#pragma unroll
            for (int j = 0; j < 4; ++j)
                bw[j] = (((byt >> (2 * j)) & 1u) ? 0x3F80u : 0u)
                      | (((byt >> (2 * j + 1)) & 1u) ? 0x3F800000u : 0u);
            const s16x8 By = __builtin_bit_cast(s16x8, bw);
#pragma unroll
            for (int ot = 0; ot < 4; ++ot) {
                acc[t][ot] = MFMA(Ah[ot], By, acc[t][ot]);
                acc[t][ot] = MFMA(Al[ot], By, acc[t][ot]);
            }
        }

        if (ks < 15) {
#pragma unroll
            for (int t = 0; t < TT; ++t) { kvc[t] = kvn[t]; avc[t] = avn[t]; }
        }
        __syncthreads();                      // glds(ks+1) complete; cur free
        cur ^= 1;
    }

    // ---- epilogue: fp64 BN (bias folded) + LIF + store + flags ----
#pragma unroll
    for (int ot = 0; ot < 4; ++ot)
#pragma unroll
        for (int r = 0; r < 4; ++r) {
            const int o = o0 + worow + ot * 16 + rowD[r];
            const int hwD = hw0 + whw + colD[r];
            const double inv = bnc[(size_t)(2 * CCH + o) * 2];
            const double add = bnc[(size_t)(2 * CCH + o) * 2 + 1];
            double v = 0.0; bool fl = false;
#pragma unroll
            for (int t = 0; t < TT; ++t) {
                const double y = (double)acc[t][ot][r] * inv + add;
                v = v + (y - v) * 0.5;
                if (fabs(v - 1.0) < MPROJ) fl = true;
                float s;
                if (v >= 1.0) { s = 1.0f; v = 0.0; } else { s = 0.0f; }
                out[((size_t)(t * BB + b) * CCH + o) * HWD + hwD] = s;
            }
            if (fl) {
                const unsigned int idx = atomicAdd(ctr2, 1u);
                if (idx < CAPP) list2[idx] = (uint32_t)((o << 14) | (b << 10) | hwD);
            }
        }
}

// ---------------------------------------------------------------------------
// Exact fp64 recompute of flagged proj chains; patch d_out.
// ---------------------------------------------------------------------------
__global__ __launch_bounds__(256) void k_fix_proj(
    const float* __restrict__ pw, const float* __restrict__ pb,
    const float* __restrict__ pg, const float* __restrict__ pbe,
    const float* __restrict__ pm, const float* __restrict__ pva,
    const uint32_t* __restrict__ kbits, const uint8_t* __restrict__ attn,
    const unsigned int* __restrict__ ctr2, const uint32_t* __restrict__ list2,
    float* __restrict__ out)
{
    const int lane = threadIdx.x & 63;
    const int wg = (blockIdx.x * blockDim.x + threadIdx.x) >> 6;
    const int nw = (gridDim.x * blockDim.x) >> 6;
    unsigned int n = *ctr2; if (n > CAPP) n = CAPP;

    for (unsigned int i = wg; i < n; i += nw) {
        const uint32_t e = list2[i];
        const int o = (e >> 14) & 511, b = (e >> 10) & 15, hw = e & 1023;
        const float* w = pw + (size_t)o * CCH;
        double dots[TT];
#pragma unroll
        for (int t = 0; t < TT; ++t) {
            double s = 0.0;
            for (int c = lane; c < CCH; c += 64) {
                const uint32_t kv = kbits[((size_t)(t * BB + b) * NW + (c >> 5)) * HWD + hw];
                const uint32_t av = attn[((size_t)(t * BB + b) * NHH + (c >> 6)) * HWD + hw];
                if (av && ((kv >> (c & 31)) & 1u)) s += (double)w[c];
            }
#pragma unroll
            for (int off = 32; off; off >>= 1) s += __shfl_xor(s, off);
            dots[t] = s;
        }
        if (lane == 0) {
            const double inv = (double)pg[o] / sqrt((double)pva[o] + 1e-5);
            const double add = (double)pbe[o] - (double)pm[o] * inv;
            const double bias = (double)pb[o];
            double v = 0.0;
#pragma unroll
            for (int t = 0; t < TT; ++t) {
                const double y = (dots[t] + bias) * inv + add;
                v = v + (y - v) * 0.5;
                float s;
                if (v >= 1.0) { s = 1.0f; v = 0.0; } else { s = 0.0f; }
                out[((size_t)(t * BB + b) * CCH + o) * HWD + hw] = s;
            }
        }
    }
}

extern "C" void kernel_launch(void* const* d_in, const int* in_sizes, int n_in,
                              void* d_out, int out_size, void* d_ws, size_t ws_size,
                              hipStream_t stream)
{
    (void)in_sizes; (void)n_in; (void)out_size; (void)ws_size;

    const float* x   = (const float*)d_in[0];
    const float* qw  = (const float*)d_in[1];
    const float* qg  = (const float*)d_in[2];
    const float* qbe = (const float*)d_in[3];
    const float* qm  = (const float*)d_in[4];
    const float* qv  = (const float*)d_in[5];
    const float* kw  = (const float*)d_in[6];
    const float* kg  = (const float*)d_in[7];
    const float* kbe = (const float*)d_in[8];
    const float* km  = (const float*)d_in[9];
    const float* kv  = (const float*)d_in[10];
    const float* pw  = (const float*)d_in[11];
    const float* pb  = (const float*)d_in[12];
    const float* pg  = (const float*)d_in[13];
    const float* pbe = (const float*)d_in[14];
    const float* pm  = (const float*)d_in[15];
    const float* pv  = (const float*)d_in[16];

    uint8_t* base = (uint8_t*)d_ws;
    uint32_t* qbits = (uint32_t*)base;                              // 4 MiB
    uint32_t* kbits = (uint32_t*)(base + 4194304);                  // 4 MiB
    uint8_t*  attn  = base + 8388608;                               // 512 KiB
    unsigned int* ctr = (unsigned int*)(base + 8912896);            // 256 B
    uint32_t* qklist  = (uint32_t*)(base + 8913152);                // 192 KiB
    uint32_t* prlist  = (uint32_t*)(base + 9109760);                // 64 KiB
    unsigned short* wtiles = (unsigned short*)(base + 9175296);     // 3 MiB
    double* bnc = (double*)(base + 12321024);                       // 24 KiB
    float* out = (float*)d_out;

    k_zero<<<1, 64, 0, stream>>>(ctr);
    k_prep<<<96, 256, 0, stream>>>(qw, kw, pw, qg, qbe, qm, qv,
                                   kg, kbe, km, kv, pg, pbe, pm, pv, pb,
                                   wtiles, bnc);
    k_qk<<<dim3(HWD / 32, CCH / 64, BB), 256, 0, stream>>>(
        x, wtiles, bnc, qbits, kbits, ctr, qklist);
    k_fix_qk<<<256, 256, 0, stream>>>(x, qw, qg, qbe, qm, qv,
                                      kw, kg, kbe, km, kv, ctr, qklist, qbits, kbits);
    k_attn<<<(BB * NHH * HWD) / 256, 256, 0, stream>>>(qbits, attn);
    k_proj<<<dim3(HWD / 64, CCH / 128, BB), 512, 0, stream>>>(
        wtiles, bnc, kbits, attn, out, ctr + 1, prlist);
    k_fix_proj<<<64, 256, 0, stream>>>(pw, pb, pg, pbe, pm, pv,
                                       kbits, attn, ctr + 1, prlist, out);
}

// Round 19
// 392.201 us; speedup vs baseline: 1.1156x; 1.0957x over previous
//
#include <hip/hip_runtime.h>
#include <cstdint>
#include <math.h>

#define TT 4
#define BB 16
#define CCH 512
#define HWD 1024
#define NHH 8
#define NW 16            // 512/32 channel bit-words
#define MQK 1.5e-4       // flag margin q/k (error std ~1.5e-5 -> 10 sigma)
#define MPROJ 1.0e-4     // flag margin proj
#define CAPQ 49152
#define CAPP 16384
#define WTSZ 262144      // ushorts per (mat,hi/lo) tile array: 32*16*64*8

typedef __attribute__((ext_vector_type(4))) float f32x4;
typedef __attribute__((ext_vector_type(8))) short s16x8;
typedef __attribute__((ext_vector_type(4))) uint32_t u32x4;

static __device__ __forceinline__ f32x4 MFMA(s16x8 a, s16x8 b, f32x4 c) {
    return __builtin_amdgcn_mfma_f32_16x16x32_bf16(a, b, c, 0, 0, 0);
}

// high halves of u0,u1 -> one u32
static __device__ __forceinline__ uint32_t hi_pair(uint32_t u0, uint32_t u1) {
#if __has_builtin(__builtin_amdgcn_perm)
    return __builtin_amdgcn_perm(u1, u0, 0x07060302u);
#else
    return (u1 & 0xFFFF0000u) | (u0 >> 16);
#endif
}

struct SplitPair { uint32_t h, l; };

// truncation split: x = bf(h) + bf(l) + r, |r| <= 2^-15 |x|
static __device__ __forceinline__ SplitPair split_pair(float f0, float f1) {
    const uint32_t u0 = __builtin_bit_cast(uint32_t, f0);
    const uint32_t u1 = __builtin_bit_cast(uint32_t, f1);
    SplitPair r;
    r.h = hi_pair(u0, u1);
    const float r0 = f0 - __builtin_bit_cast(float, u0 & 0xFFFF0000u);
    const float r1 = f1 - __builtin_bit_cast(float, u1 & 0xFFFF0000u);
    r.l = hi_pair(__builtin_bit_cast(uint32_t, r0), __builtin_bit_cast(uint32_t, r1));
    return r;
}

static __device__ __forceinline__ void load_split_frag(const float* p, s16x8& h, s16x8& l) {
    const float4 a = *(const float4*)p;
    const float4 b4 = *(const float4*)(p + 4);
    u32x4 hw_, lw_;
    const SplitPair p0 = split_pair(a.x, a.y);
    const SplitPair p1 = split_pair(a.z, a.w);
    const SplitPair p2 = split_pair(b4.x, b4.y);
    const SplitPair p3 = split_pair(b4.z, b4.w);
    hw_[0] = p0.h; lw_[0] = p0.l;
    hw_[1] = p1.h; lw_[1] = p1.l;
    hw_[2] = p2.h; lw_[2] = p2.l;
    hw_[3] = p3.h; lw_[3] = p3.l;
    h = __builtin_bit_cast(s16x8, hw_);
    l = __builtin_bit_cast(s16x8, lw_);
}

// async global->LDS 16B per lane (LDS dest = wave-uniform base + lane*16)
static __device__ __forceinline__ void glds16(const float* g, float* l) {
    __builtin_amdgcn_global_load_lds(
        (const __attribute__((address_space(1))) uint32_t*)g,
        (__attribute__((address_space(3))) uint32_t*)l, 16, 0, 0);
}

// ---------------------------------------------------------------------------
// Layout self-probe for mfma_f32_16x16x32_bf16 (verified on HW in R6-R17).
// ---------------------------------------------------------------------------
static __device__ __forceinline__ void probe_bf16(int lane, int rowD[4], int colD[4],
                                                  int& aRow, int& aKb, int& bCol, int& bKb)
{
    const f32x4 z = {0.f, 0.f, 0.f, 0.f};
    const short lv = (short)(__builtin_bit_cast(uint32_t, (float)lane) >> 16);
    const short one = (short)0x3F80;
    const s16x8 av = {lv, lv, lv, lv, lv, lv, lv, lv};
    const s16x8 ov = {one, one, one, one, one, one, one, one};
    const f32x4 pa = MFMA(av, ov, z);
    const f32x4 pb = MFMA(ov, av, z);
    bool A2 = false, B2 = false;
#pragma unroll
    for (int r = 0; r < 4; ++r) {
        const int va = (int)pa[r];
        if (((va - 48) & 127) == 0) { rowD[r] = (va - 48) >> 7; A2 = true; }
        else                        { rowD[r] = (va - 768) >> 5; }
        const int vb = (int)pb[r];
        if (((vb - 48) & 127) == 0) { colD[r] = (vb - 48) >> 7; B2 = true; }
        else                        { colD[r] = (vb - 768) >> 5; }
    }
    aRow = A2 ? (lane >> 2) : (lane & 15);
    aKb  = A2 ? (lane & 3) * 8 : (lane >> 4) * 8;
    bCol = B2 ? (lane >> 2) : (lane & 15);
    bKb  = B2 ? (lane & 3) * 8 : (lane >> 4) * 8;
}

__global__ void k_zero(unsigned int* ctr) {
    if (threadIdx.x < 2) ctr[threadIdx.x] = 0u;
}

// ---------------------------------------------------------------------------
// Pre-pass: split q/k/proj weights into canonical MFMA-frag hi/lo tiles:
//   wt[(mat*2+hl)*WTSZ + ((ot*16+ks)*64 + kgrp*16 + row)*8 + e]
// and precompute fp64 BN constants (proj bias folded into add).
// ---------------------------------------------------------------------------
__global__ __launch_bounds__(256) void k_prep(
    const float* __restrict__ qw, const float* __restrict__ kw, const float* __restrict__ pw,
    const float* __restrict__ qg, const float* __restrict__ qbe,
    const float* __restrict__ qm, const float* __restrict__ qva,
    const float* __restrict__ kg, const float* __restrict__ kbe,
    const float* __restrict__ km, const float* __restrict__ kva,
    const float* __restrict__ pg, const float* __restrict__ pbe,
    const float* __restrict__ pm, const float* __restrict__ pva,
    const float* __restrict__ pb,
    unsigned short* __restrict__ wt, double* __restrict__ bnc)
{
    const int bx = blockIdx.x;        // 0..95
    const int mat = bx >> 5, ot = bx & 31;
    const float* W = (mat == 0) ? qw : ((mat == 1) ? kw : pw);
    unsigned short* hi = wt + (size_t)(mat * 2 + 0) * WTSZ;
    unsigned short* lo = wt + (size_t)(mat * 2 + 1) * WTSZ;
#pragma unroll
    for (int it = 0; it < 4; ++it) {
        const int j = it * 256 + threadIdx.x;   // 0..1023 chunk index
        const int ks = j >> 6, sub = j & 63;
        const int kgrp = sub >> 4, row = sub & 15;
        const float* src = W + (size_t)(ot * 16 + row) * CCH + ks * 32 + kgrp * 8;
        s16x8 h, l;
        load_split_frag(src, h, l);
        *(s16x8*)&hi[((size_t)(ot * 16 + ks) * 64 + sub) * 8] = h;
        *(s16x8*)&lo[((size_t)(ot * 16 + ks) * 64 + sub) * 8] = l;
    }
    if (ot == 0) {
        const float* g  = (mat == 0) ? qg  : ((mat == 1) ? kg  : pg);
        const float* be = (mat == 0) ? qbe : ((mat == 1) ? kbe : pbe);
        const float* mn = (mat == 0) ? qm  : ((mat == 1) ? km  : pm);
        const float* va = (mat == 0) ? qva : ((mat == 1) ? kva : pva);
        for (int o = threadIdx.x; o < CCH; o += 256) {
            const double inv = (double)g[o] / sqrt((double)va[o] + 1e-5);
            double add = (double)be[o] - (double)mn[o] * inv;
            if (mat == 2) add = add + (double)pb[o] * inv;
            bnc[(size_t)(mat * CCH + o) * 2]     = inv;
            bnc[(size_t)(mat * CCH + o) * 2 + 1] = add;
        }
    }
}

// ---------------------------------------------------------------------------
// q/k conv1x1 via bf16-split MFMA (3 cross terms). Block = 64o x 32hw,
// 4 waves (2 o-halves x 2 hw-halves), wave = 32o (2 ot) x 16hw, 2 branches.
// X staged RAW f32 via global_load_lds (swizzle on the per-lane GLOBAL
// address; LDS dest linear), double-buffered, one barrier per ks; bf16
// split at read time. fp64 BN/LIF epilogue, spikes bitpacked.  [R12 verbatim]
// ---------------------------------------------------------------------------
__global__ __launch_bounds__(256, 4) void k_qk(
    const float* __restrict__ x,
    const unsigned short* __restrict__ wt, const double* __restrict__ bnc,
    uint32_t* __restrict__ qbits, uint32_t* __restrict__ kbits,
    unsigned int* __restrict__ ctr, uint32_t* __restrict__ list)
{
    __shared__ float Xs[2][4096];           // [buf][t 4][c 32][hw-phys 32]
    __shared__ uint32_t QB[2][2][TT][32];   // [branch][o-word][t][hw]

    const int tid = threadIdx.x, lane = tid & 63, wid = tid >> 6;
    const int b   = blockIdx.z;
    const int o0  = blockIdx.y * 64, hw0 = blockIdx.x * 32;
    const int worow = (wid >> 1) * 32, whw = (wid & 1) * 16;

    int rowD[4], colD[4], aRow, aKb, bCol, bKb;
    probe_bf16(lane, rowD, colD, aRow, aKb, bCol, bKb);

    const int laneoff = ((aKb >> 3) * 16 + aRow) * 8;   // A-frag offset in tile
    const int kgrp = bKb >> 3;
    const int roff = (whw + bCol) ^ ((kgrp & 1) << 4);  // swizzled hw column
    const int otg0 = blockIdx.y * 4 + (wid >> 1) * 2;   // first 16-o tile idx

    // glds source offsets: chunk ch = it*256+tid -> (t, c, hw4-phys);
    // global hw4 = hw4p ^ ((c>>3&1)<<2)  (inverse of the LDS column swizzle)
    uint32_t gOff[4];
#pragma unroll
    for (int it = 0; it < 4; ++it) {
        const int ch = it * 256 + tid;       // 0..1023
        const int t = ch >> 8, c = (ch >> 3) & 31, hw4p = ch & 7;
        const int ghw4 = hw4p ^ (((c >> 3) & 1) << 2);
        gOff[it] = (uint32_t)(((t * BB + b) * CCH + c) * HWD + hw0 + ghw4 * 4);
    }

    f32x4 aq[TT][2], ak[TT][2];
#pragma unroll
    for (int t = 0; t < TT; ++t)
#pragma unroll
        for (int ot = 0; ot < 2; ++ot) {
            aq[t][ot] = (f32x4){0.f, 0.f, 0.f, 0.f};
            ak[t][ot] = (f32x4){0.f, 0.f, 0.f, 0.f};
        }

    auto stage = [&](int ks, int buf) {
#pragma unroll
        for (int it = 0; it < 4; ++it)
            glds16(x + (size_t)gOff[it] + (size_t)ks * (32 * HWD),
                   &Xs[buf][(it * 256 + wid * 64) * 4]);
    };

    stage(0, 0);

    int cur = 0;
#pragma unroll 1
    for (int ks = 0; ks < 16; ++ks) {
        __syncthreads();                    // glds(ks) complete; buf cur^1 free
        if (ks < 15) stage(ks + 1, cur ^ 1);

        const size_t tb0 = ((size_t)(otg0 + 0) * 16 + ks) * 512 + laneoff;
        const size_t tb1 = ((size_t)(otg0 + 1) * 16 + ks) * 512 + laneoff;
        const s16x8 Aqh0 = *(const s16x8*)&wt[0 * WTSZ + tb0];
        const s16x8 Aql0 = *(const s16x8*)&wt[1 * WTSZ + tb0];
        const s16x8 Akh0 = *(const s16x8*)&wt[2 * WTSZ + tb0];
        const s16x8 Akl0 = *(const s16x8*)&wt[3 * WTSZ + tb0];
        const s16x8 Aqh1 = *(const s16x8*)&wt[0 * WTSZ + tb1];
        const s16x8 Aql1 = *(const s16x8*)&wt[1 * WTSZ + tb1];
        const s16x8 Akh1 = *(const s16x8*)&wt[2 * WTSZ + tb1];
        const s16x8 Akl1 = *(const s16x8*)&wt[3 * WTSZ + tb1];

        const float* Bb = Xs[cur];
#pragma unroll
        for (int t = 0; t < TT; ++t) {
            const float* Bp = Bb + (t * 32 + kgrp * 8) * 32 + roff;
            float w[8];
#pragma unroll
            for (int e = 0; e < 8; ++e) w[e] = Bp[e * 32];
            u32x4 bh, bl;
#pragma unroll
            for (int p = 0; p < 4; ++p) {
                const SplitPair sp = split_pair(w[2 * p], w[2 * p + 1]);
                bh[p] = sp.h; bl[p] = sp.l;
            }
            const s16x8 Bh = __builtin_bit_cast(s16x8, bh);
            const s16x8 Bl = __builtin_bit_cast(s16x8, bl);

            aq[t][0] = MFMA(Aqh0, Bh, aq[t][0]);
            aq[t][0] = MFMA(Aqh0, Bl, aq[t][0]);
            aq[t][0] = MFMA(Aql0, Bh, aq[t][0]);
            ak[t][0] = MFMA(Akh0, Bh, ak[t][0]);
            ak[t][0] = MFMA(Akh0, Bl, ak[t][0]);
            ak[t][0] = MFMA(Akl0, Bh, ak[t][0]);
            aq[t][1] = MFMA(Aqh1, Bh, aq[t][1]);
            aq[t][1] = MFMA(Aqh1, Bl, aq[t][1]);
            aq[t][1] = MFMA(Aql1, Bh, aq[t][1]);
            ak[t][1] = MFMA(Akh1, Bh, ak[t][1]);
            ak[t][1] = MFMA(Akh1, Bl, ak[t][1]);
            ak[t][1] = MFMA(Akl1, Bh, ak[t][1]);
        }
        cur ^= 1;
    }

    // ---- epilogue: fp64 BN + LIF, flags, bitpack ----
    {
        int dum0, dum1, dum2, dum3;
        probe_bf16(lane, rowD, colD, dum0, dum1, dum2, dum3);  // rematerialize
    }
    ((uint32_t*)QB)[tid] = 0u;
    ((uint32_t*)QB)[tid + 256] = 0u;
    __syncthreads();

    auto chains = [&](f32x4 (&acc)[TT][2], int br) {
#pragma unroll
        for (int ot = 0; ot < 2; ++ot)
#pragma unroll
            for (int r = 0; r < 4; ++r) {
                const int orow = worow + ot * 16 + rowD[r];    // 0..63
                const int o = o0 + orow;
                const double inv = bnc[(size_t)(br * CCH + o) * 2];
                const double add = bnc[(size_t)(br * CCH + o) * 2 + 1];
                const uint32_t bit = 1u << (orow & 31);
                const int ow = orow >> 5;
                const int hwq = whw + colD[r];                 // 0..31
                double v = 0.0; bool fl = false;
#pragma unroll
                for (int t = 0; t < TT; ++t) {
                    const double y = (double)acc[t][ot][r] * inv + add;
                    v = v + (y - v) * 0.5;
                    if (fabs(v - 1.0) < MQK) fl = true;
                    if (v >= 1.0) { atomicOr(&QB[br][ow][t][hwq], bit); v = 0.0; }
                }
                if (fl) {
                    const unsigned int idx = atomicAdd(ctr, 1u);
                    if (idx < CAPQ)
                        list[idx] = (uint32_t)((br << 23) | (o << 14) | (b << 10) | (hw0 + hwq));
                }
            }
    };
    chains(aq, 0);
    chains(ak, 1);
    __syncthreads();

#pragma unroll
    for (int u = 0; u < 2; ++u) {
        const int idx = tid + u * 256;   // 0..511
        const int br = idx >> 8, ow = (idx >> 7) & 1, t = (idx >> 5) & 3, hwq = idx & 31;
        uint32_t* dst = br ? kbits : qbits;
        dst[((size_t)(t * BB + b) * NW + (o0 >> 5) + ow) * HWD + hw0 + hwq] = QB[br][ow][t][hwq];
    }
}

// ---------------------------------------------------------------------------
// Exact fp64 recompute of flagged q/k chains; patch spike bits.
// ---------------------------------------------------------------------------
__global__ __launch_bounds__(256) void k_fix_qk(
    const float* __restrict__ x,
    const float* __restrict__ qw, const float* __restrict__ qg, const float* __restrict__ qbe,
    const float* __restrict__ qm, const float* __restrict__ qva,
    const float* __restrict__ kw, const float* __restrict__ kg, const float* __restrict__ kbe,
    const float* __restrict__ km, const float* __restrict__ kva,
    const unsigned int* __restrict__ ctr, const uint32_t* __restrict__ list,
    uint32_t* __restrict__ qbits, uint32_t* __restrict__ kbits)
{
    const int lane = threadIdx.x & 63;
    const int wg = (blockIdx.x * blockDim.x + threadIdx.x) >> 6;
    const int nw = (gridDim.x * blockDim.x) >> 6;
    unsigned int n = *ctr; if (n > CAPQ) n = CAPQ;

    for (unsigned int i = wg; i < n; i += nw) {
        const uint32_t e = list[i];
        const int br = (e >> 23) & 1, o = (e >> 14) & 511, b = (e >> 10) & 15, hw = e & 1023;
        const float* w = (br ? kw : qw) + (size_t)o * CCH;
        double dots[TT];
#pragma unroll
        for (int t = 0; t < TT; ++t) {
            double s = 0.0;
            for (int c = lane; c < CCH; c += 64)
                s += (double)w[c] * (double)x[((size_t)(t * BB + b) * CCH + c) * HWD + hw];
#pragma unroll
            for (int off = 32; off; off >>= 1) s += __shfl_xor(s, off);
            dots[t] = s;
        }
        if (lane == 0) {
            const float* g  = br ? kg  : qg;
            const float* be = br ? kbe : qbe;
            const float* mn = br ? km  : qm;
            const float* va = br ? kva : qva;
            const double inv = (double)g[o] / sqrt((double)va[o] + 1e-5);
            const double add = (double)be[o] - (double)mn[o] * inv;
            uint32_t* bits = br ? kbits : qbits;
            double v = 0.0;
#pragma unroll
            for (int t = 0; t < TT; ++t) {
                const double y = dots[t] * inv + add;
                v = v + (y - v) * 0.5;
                const size_t wa = ((size_t)(t * BB + b) * NW + (o >> 5)) * HWD + hw;
                const uint32_t bit = 1u << (o & 31);
                if (v >= 1.0) { atomicOr(&bits[wa], bit); v = 0.0; }
                else          { atomicAnd(&bits[wa], ~bit); }
            }
        }
    }
}

// ---------------------------------------------------------------------------
// Head-sum of q spikes (popcount) + LIF at 0.5 (exact dyadic).
// ---------------------------------------------------------------------------
__global__ __launch_bounds__(256) void k_attn(
    const uint32_t* __restrict__ qbits, uint8_t* __restrict__ attn)
{
    const int idx = blockIdx.x * 256 + threadIdx.x;
    const int hw = idx & (HWD - 1);
    const int h  = (idx >> 10) & (NHH - 1);
    const int b  = idx >> 13;
    double v = 0.0;
#pragma unroll
    for (int t = 0; t < TT; ++t) {
        const uint32_t w0 = qbits[((size_t)(t * BB + b) * NW + h * 2    ) * HWD + hw];
        const uint32_t w1 = qbits[((size_t)(t * BB + b) * NW + h * 2 + 1) * HWD + hw];
        const double q = (double)(__popc(w0) + __popc(w1));
        v = v + (q - v) * 0.5;
        const uint8_t s = (v >= 0.5) ? (uint8_t)1 : (uint8_t)0;
        attn[((size_t)(t * BB + b) * NHH + h) * HWD + hw] = s;
        if (s) v = 0.0;
    }
}

// ---------------------------------------------------------------------------
// proj conv via bf16 MFMA over binary y = attn & k. A hi/lo planes staged
// per-ks via global_load_lds (shared across waves, removes duplicate global
// loads), double-buffered, one barrier/ks; kv/av software-prefetched one ks
// ahead. fp64 bias/BN/LIF + flags. Block = 128o x 32hw, 4 waves.
// ---------------------------------------------------------------------------
__global__ __launch_bounds__(256, 3) void k_proj(
    const unsigned short* __restrict__ wt, const double* __restrict__ bnc,
    const uint32_t* __restrict__ kbits, const uint8_t* __restrict__ attn,
    float* __restrict__ out,
    unsigned int* __restrict__ ctr2, uint32_t* __restrict__ list2)
{
    __shared__ __align__(16) unsigned short Aw[2][2][8][512];  // [buf][plane][otl][frag]

    const int tid = threadIdx.x, lane = tid & 63, wid = tid >> 6;
    const int b   = blockIdx.z;
    const int o0  = blockIdx.y * 128, hw0 = blockIdx.x * 32;
    const int worow = (wid >> 1) * 64, whw = (wid & 1) * 16;

    int rowD[4], colD[4], aRow, aKb, bCol, bKb;
    probe_bf16(lane, rowD, colD, aRow, aKb, bCol, bKb);
    const int laneoff = ((aKb >> 3) * 16 + aRow) * 8;
    const int hwB = hw0 + whw + bCol;
    const int otl0 = (wid >> 1) * 4;          // this wave's local ot base

    f32x4 acc[TT][4];
#pragma unroll
    for (int t = 0; t < TT; ++t)
#pragma unroll
        for (int ot = 0; ot < 4; ++ot) acc[t][ot] = (f32x4){0.f, 0.f, 0.f, 0.f};

    // glds staging: 16 chunks of 1KB (plane x 8 local ot tiles), 4 per wave
    auto stageA = [&](int ks, int buf) {
#pragma unroll
        for (int i = 0; i < 4; ++i) {
            const int ch = wid * 4 + i;       // 0..15
            const int plane = ch >> 3, otl = ch & 7;
            const unsigned short* src = wt + (size_t)(4 + plane) * WTSZ
                + ((size_t)(blockIdx.y * 8 + otl) * 16 + ks) * 512 + (size_t)lane * 8;
            glds16((const float*)src, (float*)&Aw[buf][plane][otl][0]);
        }
    };

    uint32_t kvc[TT], avc[TT], kvn[TT], avn[TT];
    auto loadB = [&](int ks, uint32_t kv[TT], uint32_t av[TT]) {
#pragma unroll
        for (int t = 0; t < TT; ++t) {
            const size_t tb = (size_t)(t * BB + b);
            kv[t] = kbits[(tb * NW + ks) * HWD + hwB];
            av[t] = attn[(tb * NHH + (ks >> 1)) * HWD + hwB];
        }
    };

    stageA(0, 0);
    loadB(0, kvc, avc);
    __syncthreads();                          // glds(0) complete

    int cur = 0;
#pragma unroll 1
    for (int ks = 0; ks < 16; ++ks) {
        if (ks < 15) { stageA(ks + 1, cur ^ 1); loadB(ks + 1, kvn, avn); }

        s16x8 Ah[4], Al[4];
#pragma unroll
        for (int ot = 0; ot < 4; ++ot) {
            Ah[ot] = *(const s16x8*)&Aw[cur][0][otl0 + ot][laneoff];
            Al[ot] = *(const s16x8*)&Aw[cur][1][otl0 + ot][laneoff];
        }
#pragma unroll
        for (int t = 0; t < TT; ++t) {
            const uint32_t mask = avc[t] ? kvc[t] : 0u;
            const uint32_t byt = (mask >> bKb) & 0xFFu;
            u32x4 bw;
#pragma unroll
            for (int j = 0; j < 4; ++j)
                bw[j] = (((byt >> (2 * j)) & 1u) ? 0x3F80u : 0u)
                      | (((byt >> (2 * j + 1)) & 1u) ? 0x3F800000u : 0u);
            const s16x8 By = __builtin_bit_cast(s16x8, bw);
#pragma unroll
            for (int ot = 0; ot < 4; ++ot) {
                acc[t][ot] = MFMA(Ah[ot], By, acc[t][ot]);
                acc[t][ot] = MFMA(Al[ot], By, acc[t][ot]);
            }
        }

        if (ks < 15) {
#pragma unroll
            for (int t = 0; t < TT; ++t) { kvc[t] = kvn[t]; avc[t] = avn[t]; }
        }
        __syncthreads();                      // glds(ks+1) complete; cur free
        cur ^= 1;
    }

    // ---- epilogue: fp64 BN (bias folded) + LIF + store + flags ----
#pragma unroll
    for (int ot = 0; ot < 4; ++ot)
#pragma unroll
        for (int r = 0; r < 4; ++r) {
            const int o = o0 + worow + ot * 16 + rowD[r];
            const int hwD = hw0 + whw + colD[r];
            const double inv = bnc[(size_t)(2 * CCH + o) * 2];
            const double add = bnc[(size_t)(2 * CCH + o) * 2 + 1];
            double v = 0.0; bool fl = false;
#pragma unroll
            for (int t = 0; t < TT; ++t) {
                const double y = (double)acc[t][ot][r] * inv + add;
                v = v + (y - v) * 0.5;
                if (fabs(v - 1.0) < MPROJ) fl = true;
                float s;
                if (v >= 1.0) { s = 1.0f; v = 0.0; } else { s = 0.0f; }
                out[((size_t)(t * BB + b) * CCH + o) * HWD + hwD] = s;
            }
            if (fl) {
                const unsigned int idx = atomicAdd(ctr2, 1u);
                if (idx < CAPP) list2[idx] = (uint32_t)((o << 14) | (b << 10) | hwD);
            }
        }
}

// ---------------------------------------------------------------------------
// Exact fp64 recompute of flagged proj chains; patch d_out.
// ---------------------------------------------------------------------------
__global__ __launch_bounds__(256) void k_fix_proj(
    const float* __restrict__ pw, const float* __restrict__ pb,
    const float* __restrict__ pg, const float* __restrict__ pbe,
    const float* __restrict__ pm, const float* __restrict__ pva,
    const uint32_t* __restrict__ kbits, const uint8_t* __restrict__ attn,
    const unsigned int* __restrict__ ctr2, const uint32_t* __restrict__ list2,
    float* __restrict__ out)
{
    const int lane = threadIdx.x & 63;
    const int wg = (blockIdx.x * blockDim.x + threadIdx.x) >> 6;
    const int nw = (gridDim.x * blockDim.x) >> 6;
    unsigned int n = *ctr2; if (n > CAPP) n = CAPP;

    for (unsigned int i = wg; i < n; i += nw) {
        const uint32_t e = list2[i];
        const int o = (e >> 14) & 511, b = (e >> 10) & 15, hw = e & 1023;
        const float* w = pw + (size_t)o * CCH;
        double dots[TT];
#pragma unroll
        for (int t = 0; t < TT; ++t) {
            double s = 0.0;
            for (int c = lane; c < CCH; c += 64) {
                const uint32_t kv = kbits[((size_t)(t * BB + b) * NW + (c >> 5)) * HWD + hw];
                const uint32_t av = attn[((size_t)(t * BB + b) * NHH + (c >> 6)) * HWD + hw];
                if (av && ((kv >> (c & 31)) & 1u)) s += (double)w[c];
            }
#pragma unroll
            for (int off = 32; off; off >>= 1) s += __shfl_xor(s, off);
            dots[t] = s;
        }
        if (lane == 0) {
            const double inv = (double)pg[o] / sqrt((double)pva[o] + 1e-5);
            const double add = (double)pbe[o] - (double)pm[o] * inv;
            const double bias = (double)pb[o];
            double v = 0.0;
#pragma unroll
            for (int t = 0; t < TT; ++t) {
                const double y = (dots[t] + bias) * inv + add;
                v = v + (y - v) * 0.5;
                float s;
                if (v >= 1.0) { s = 1.0f; v = 0.0; } else { s = 0.0f; }
                out[((size_t)(t * BB + b) * CCH + o) * HWD + hw] = s;
            }
        }
    }
}

extern "C" void kernel_launch(void* const* d_in, const int* in_sizes, int n_in,
                              void* d_out, int out_size, void* d_ws, size_t ws_size,
                              hipStream_t stream)
{
    (void)in_sizes; (void)n_in; (void)out_size; (void)ws_size;

    const float* x   = (const float*)d_in[0];
    const float* qw  = (const float*)d_in[1];
    const float* qg  = (const float*)d_in[2];
    const float* qbe = (const float*)d_in[3];
    const float* qm  = (const float*)d_in[4];
    const float* qv  = (const float*)d_in[5];
    const float* kw  = (const float*)d_in[6];
    const float* kg  = (const float*)d_in[7];
    const float* kbe = (const float*)d_in[8];
    const float* km  = (const float*)d_in[9];
    const float* kv  = (const float*)d_in[10];
    const float* pw  = (const float*)d_in[11];
    const float* pb  = (const float*)d_in[12];
    const float* pg  = (const float*)d_in[13];
    const float* pbe = (const float*)d_in[14];
    const float* pm  = (const float*)d_in[15];
    const float* pv  = (const float*)d_in[16];

    uint8_t* base = (uint8_t*)d_ws;
    uint32_t* qbits = (uint32_t*)base;                              // 4 MiB
    uint32_t* kbits = (uint32_t*)(base + 4194304);                  // 4 MiB
    uint8_t*  attn  = base + 8388608;                               // 512 KiB
    unsigned int* ctr = (unsigned int*)(base + 8912896);            // 256 B
    uint32_t* qklist  = (uint32_t*)(base + 8913152);                // 192 KiB
    uint32_t* prlist  = (uint32_t*)(base + 9109760);                // 64 KiB
    unsigned short* wtiles = (unsigned short*)(base + 9175296);     // 3 MiB
    double* bnc = (double*)(base + 12321024);                       // 24 KiB
    float* out = (float*)d_out;

    k_zero<<<1, 64, 0, stream>>>(ctr);
    k_prep<<<96, 256, 0, stream>>>(qw, kw, pw, qg, qbe, qm, qv,
                                   kg, kbe, km, kv, pg, pbe, pm, pv, pb,
                                   wtiles, bnc);
    k_qk<<<dim3(HWD / 32, CCH / 64, BB), 256, 0, stream>>>(
        x, wtiles, bnc, qbits, kbits, ctr, qklist);
    k_fix_qk<<<256, 256, 0, stream>>>(x, qw, qg, qbe, qm, qv,
                                      kw, kg, kbe, km, kv, ctr, qklist, qbits, kbits);
    k_attn<<<(BB * NHH * HWD) / 256, 256, 0, stream>>>(qbits, attn);
    k_proj<<<dim3(HWD / 32, CCH / 128, BB), 256, 0, stream>>>(
        wtiles, bnc, kbits, attn, out, ctr + 1, prlist);
    k_fix_proj<<<64, 256, 0, stream>>>(pw, pb, pg, pbe, pm, pv,
                                       kbits, attn, ctr + 1, prlist, out);
}